// Round 9
// baseline (663.804 us; speedup 1.0000x reference)
//
#include <hip/hip_runtime.h>
#include <math.h>

// Problem constants
#define Bc 4
#define Tc 1024
#define DMc 1024
#define Hc 16
#define DKc 64
#define BHc 64          // B*H
#define Mc 4096         // B*T
#define TD (Tc*DKc)     // 65536 el per (b,h) slab, stride-64 layout
#define TD2 (Tc*128)    // combined re|im slab, stride-128 layout
#define TDS (128*2048)  // split-D slab: [d(128)][s hi 1024 | s lo 1024] bf16

typedef __bf16 bf16_t;
typedef bf16_t bf16x4 __attribute__((ext_vector_type(4)));
typedef bf16_t bf16x8 __attribute__((ext_vector_type(8)));
typedef float  f32x4  __attribute__((ext_vector_type(4)));

#define KLSTR 136  // prop: K tile row stride (bf16): [hi 64|lo 64|pad 8] — 272B, 16B-aligned rows
#define DLSTR 72   // prop: D tile row stride (bf16): [hi 32|lo 32|pad 8] — 144B, 16B-aligned rows

__device__ __forceinline__ bf16x8 ld8(const bf16_t* p) {
    return *(const bf16x8*)p;   // ds_read_b128 (all call sites 16B-aligned)
}
__device__ __forceinline__ void packsplit4(bf16_t* dh, bf16_t* dl, float4 v) {
    bf16x4 h, l;
    h[0]=(bf16_t)v.x; l[0]=(bf16_t)(v.x-(float)h[0]);
    h[1]=(bf16_t)v.y; l[1]=(bf16_t)(v.y-(float)h[1]);
    h[2]=(bf16_t)v.z; l[2]=(bf16_t)(v.z-(float)h[2]);
    h[3]=(bf16_t)v.w; l[3]=(bf16_t)(v.w-(float)h[3]);
    *(bf16x4*)dh = h; *(bf16x4*)dl = l;
}
__device__ __forceinline__ unsigned pk2(bf16_t a, bf16_t b) {
    unsigned short ua = __builtin_bit_cast(unsigned short, a);
    unsigned short ub = __builtin_bit_cast(unsigned short, b);
    return (unsigned)ua | ((unsigned)ub << 16);
}
// async global->LDS, 16B per lane; lds dest must be wave-uniform base.
__device__ __forceinline__ void gload16(const bf16_t* g, bf16_t* l) {
    __builtin_amdgcn_global_load_lds(
        (__attribute__((address_space(1))) void*)(bf16_t*)g,
        (__attribute__((address_space(3))) void*)l, 16, 0, 0);
}

// ---------------------------------------------------------------------------
// Convert x (4096x1024 f32) -> xh, xl bf16
// ---------------------------------------------------------------------------
__global__ __launch_bounds__(256)
void convx_k(const float* __restrict__ x,
             bf16_t* __restrict__ xh, bf16_t* __restrict__ xl)
{
    size_t i = ((size_t)blockIdx.x * 256 + threadIdx.x) * 4;
    float4 v = *(const float4*)&x[i];
    packsplit4(&xh[i], &xl[i], v);
}

// ---------------------------------------------------------------------------
// Convert + transpose each W (1024x1024 f32 [k][n]) -> WT hi/lo bf16 [n][k].
// ---------------------------------------------------------------------------
__global__ __launch_bounds__(256)
void convw_k(const float* __restrict__ W0, const float* __restrict__ W1,
             const float* __restrict__ W2, const float* __restrict__ W3,
             const float* __restrict__ W4, const float* __restrict__ W5,
             bf16_t* __restrict__ WT)
{
    __shared__ float tile[32][33];
    const float* Ws[6] = {W0, W1, W2, W3, W4, W5};
    const int wi = blockIdx.z;
    const float* W = Ws[wi];
    bf16_t* WTh = WT + (size_t)wi * 2097152;
    bf16_t* WTl = WTh + 1048576;

    const int tx = threadIdx.x & 31, ty = threadIdx.x >> 5;
    const int k0 = blockIdx.x * 32, n0 = blockIdx.y * 32;
#pragma unroll
    for (int i = 0; i < 4; i++)
        tile[ty + 8*i][tx] = W[(size_t)(k0 + ty + 8*i) * DMc + n0 + tx];
    __syncthreads();
    const int kg = threadIdx.x & 7, n = threadIdx.x >> 3;
    float4 v = make_float4(tile[kg*4+0][n], tile[kg*4+1][n],
                           tile[kg*4+2][n], tile[kg*4+3][n]);
    const size_t o = (size_t)(n0 + n) * DMc + k0 + kg*4;
    packsplit4(&WTh[o], &WTl[o], v);
}

// ---------------------------------------------------------------------------
// Split-bf16 MFMA GEMM (3 products, f32 accum). A [m][k] hi/lo; B = WT [n][k].
// Staging via global_load_lds width=16 into linear [128][32] LDS tiles.
// ---------------------------------------------------------------------------
template<int MODE>
__global__ __launch_bounds__(256)
void mgemm_k(const bf16_t* __restrict__ Ah, const bf16_t* __restrict__ Al,
             const bf16_t* __restrict__ WT,
             bf16_t* __restrict__ Oq, bf16_t* __restrict__ Ok,
             bf16_t* __restrict__ Od, float* __restrict__ Ov,
             float* __restrict__ Of)
{
    __shared__ bf16_t S[4][128*32];   // 32 KB: Ash, Asl, Bsh, Bsl (linear)

    const int tid = threadIdx.x;
    const int wv  = tid >> 6;
    const int ln  = tid & 63;
    const int l15 = ln & 15;
    const int qd  = ln >> 4;
    const int m0  = blockIdx.x * 128;
    const int by  = blockIdx.y;

    const bf16_t *Bh, *Bl;
    int n0, sel, kt0, kt1;
    float* Opart;
    if (MODE == 0) {
        sel = by >> 3;
        n0 = (by & 7) * 128;
        Bh = WT + (size_t)sel * 2097152;
        Bl = Bh + 1048576;
        kt0 = 0; kt1 = DMc;
        Opart = nullptr;
    } else {
        sel = 5;
        Bh = WT + (size_t)5 * 2097152;
        Bl = Bh + 1048576;
        n0 = by * 128;
        kt0 = blockIdx.z * 256; kt1 = kt0 + 256;
        Opart = Of + (size_t)blockIdx.z * ((size_t)Mc * DMc);
    }

    // staging geometry: per instr i (0..7), lane ln covers LDS elements
    // [i*512 + ln*8, +8)  ->  row = i*16 + (ln>>2), col = (ln&3)*8
    const int srow = ln >> 2;
    const int scol = (ln & 3) * 8;
    const bf16_t* sbase;
    if (wv == 0)      sbase = Ah + (size_t)(m0 + srow) * DMc + scol;
    else if (wv == 1) sbase = Al + (size_t)(m0 + srow) * DMc + scol;
    else if (wv == 2) sbase = Bh + (size_t)(n0 + srow) * DMc + scol;
    else              sbase = Bl + (size_t)(n0 + srow) * DMc + scol;
    sbase += kt0;
    bf16_t* ldst = &S[wv][0];

    f32x4 acc[4][4];
#pragma unroll
    for (int i = 0; i < 4; i++)
#pragma unroll
        for (int j = 0; j < 4; j++) acc[i][j] = (f32x4)0.f;

#pragma unroll 1
    for (int kt = kt0; kt < kt1; kt += 32) {
        __syncthreads();   // previous tile fully consumed
#pragma unroll
        for (int i = 0; i < 8; i++)
            gload16(sbase + (size_t)i * 16 * DMc, ldst + i * 512);
        sbase += 32;
        __syncthreads();   // vmcnt drained before barrier -> tile visible

        bf16x8 fah[4], fal[4], fbh[4], fbl[4];
#pragma unroll
        for (int it = 0; it < 4; it++) {
            const int row = ((wv>>1)*64 + it*16 + l15) * 32 + qd*8;
            fah[it] = *(const bf16x8*)&S[0][row];
            fal[it] = *(const bf16x8*)&S[1][row];
        }
#pragma unroll
        for (int jt = 0; jt < 4; jt++) {
            const int row = ((wv&1)*64 + jt*16 + l15) * 32 + qd*8;
            fbh[jt] = *(const bf16x8*)&S[2][row];
            fbl[jt] = *(const bf16x8*)&S[3][row];
        }
#pragma unroll
        for (int it = 0; it < 4; it++)
#pragma unroll
            for (int jt = 0; jt < 4; jt++) {
                acc[it][jt] = __builtin_amdgcn_mfma_f32_16x16x32_bf16(
                    fah[it], fbh[jt], acc[it][jt], 0, 0, 0);
                acc[it][jt] = __builtin_amdgcn_mfma_f32_16x16x32_bf16(
                    fah[it], fbl[jt], acc[it][jt], 0, 0, 0);
                acc[it][jt] = __builtin_amdgcn_mfma_f32_16x16x32_bf16(
                    fal[it], fbh[jt], acc[it][jt], 0, 0, 0);
            }
    }

#pragma unroll
    for (int it = 0; it < 4; it++) {
        const int mb = m0 + (wv>>1)*64 + it*16 + qd*4;
#pragma unroll
        for (int jt = 0; jt < 4; jt++) {
            const int col = n0 + (wv&1)*64 + jt*16 + l15;
            if (MODE == 0) {
                const int hh = col >> 6;
                const int b  = mb >> 10, t0 = mb & 1023;
                if (sel <= 1) {
                    bf16_t* O = sel ? Ok : Oq;
                    const int d = col & 63;
#pragma unroll
                    for (int r = 0; r < 4; r++) {
                        const float val = acc[it][jt][r];
                        const size_t o = ((size_t)(b*Hc + hh)*Tc + t0 + r)*128 + d;
                        bf16_t vh = (bf16_t)val;
                        O[o]      = vh;
                        O[o + 64] = (bf16_t)(val - (float)vh);
                    }
                } else if (sel <= 3) {
                    // transposed split-D: [bh][d][t hi | t lo]
                    const int d = (sel == 3 ? 64 : 0) + (col & 63);
                    bf16x4 h4, l4;
#pragma unroll
                    for (int r = 0; r < 4; r++) {
                        const float val = acc[it][jt][r];
                        h4[r] = (bf16_t)val;
                        l4[r] = (bf16_t)(val - (float)h4[r]);
                    }
                    const size_t o = (size_t)(b*Hc + hh)*TDS + (size_t)d*2048 + t0;
                    *(bf16x4*)&Od[o]        = h4;
                    *(bf16x4*)&Od[o + 1024] = l4;
                } else {
#pragma unroll
                    for (int r = 0; r < 4; r++)
                        Ov[((size_t)(b*Hc + hh)*Tc + t0 + r)*64 + (col & 63)]
                            = acc[it][jt][r];
                }
            } else {
#pragma unroll
                for (int r = 0; r < 4; r++)
                    Opart[(size_t)(mb + r) * DMc + col] = acc[it][jt][r];
            }
        }
    }
}

// ---------------------------------------------------------------------------
// Sum 4 K-slice partials -> out
// ---------------------------------------------------------------------------
__global__ __launch_bounds__(256)
void reduce4_k(const float* __restrict__ p0, const float* __restrict__ p1,
               const float* __restrict__ p2, const float* __restrict__ p3,
               float* __restrict__ out)
{
    size_t i = ((size_t)blockIdx.x * 256 + threadIdx.x) * 4;
    float4 a = *(const float4*)&p0[i];
    float4 b = *(const float4*)&p1[i];
    float4 c = *(const float4*)&p2[i];
    float4 d = *(const float4*)&p3[i];
    *(float4*)&out[i] = make_float4(a.x+b.x+c.x+d.x, a.y+b.y+c.y+d.y,
                                    a.z+b.z+c.z+d.z, a.w+b.w+c.w+d.w);
}

// ---------------------------------------------------------------------------
// Fused propagation step (r5 structure + double-buffered LDS, 1 barrier/chunk):
// 256 threads, grid (64,8) -> 2 blocks/CU (measured best: r5=119 vs r7=134
// (4 blk/CU) vs r8=132 (1 blk/CU)).  Loop: {prefetch ch+1 -> regs; compute
// chunk ch from buf[ch&1]; write regs -> buf[(ch+1)&1]; barrier}.  Hazards:
// write to buf[cur^1] follows iter ch-1's barrier which follows all its
// reads of buf[cur^1]; reads of buf[cur] follow iter ch-1's barrier after
// its writes.  Arithmetic and MFMA order identical to r5 (bitwise-same).
// ---------------------------------------------------------------------------
template<int FINAL>
__global__ __launch_bounds__(256)
void prop_k(const bf16_t* __restrict__ Qg, const bf16_t* __restrict__ Kg,
            const bf16_t* __restrict__ DTin, bf16_t* __restrict__ DTout,
            float* __restrict__ Dc, const float* __restrict__ llam)
{
    __shared__ bf16_t Ks[2][32*KLSTR];    // 2 x 8.7 KB
    __shared__ bf16_t Ds[2][128*DLSTR];   // 2 x 18.4 KB  (54 KB total)

    const int tid = threadIdx.x;
    const int wv  = tid >> 6;
    const int ln  = tid & 63;
    const int l15 = ln & 15;
    const int qd  = ln >> 4;
    const int bh  = blockIdx.x;
    const int Tw  = blockIdx.y * 128 + wv * 32;   // this wave's 32 t's

    const bf16_t* Qh  = Qg   + (size_t)bh * (Tc*128);
    const bf16_t* Kh  = Kg   + (size_t)bh * (Tc*128);
    const bf16_t* DTh = DTin + (size_t)bh * TDS;

    // Q B-fragments (lane n=t=l15, k=dk=qd*8+j), loop-invariant
    bf16x8 qfh[2][2], qfl[2][2];     // [tj][ks]
#pragma unroll
    for (int tj = 0; tj < 2; tj++) {
        const bf16_t* qp = &Qh[(size_t)(Tw + tj*16 + l15) * 128];
#pragma unroll
        for (int ks = 0; ks < 2; ks++) {
            qfh[tj][ks] = *(const bf16x8*)&qp[ks*32 + qd*8];
            qfl[tj][ks] = *(const bf16x8*)&qp[64 + ks*32 + qd*8];
        }
    }

    // staging geometry (loop-invariant per-thread src / LDS offsets)
    const int idk0 = tid, idk1 = tid + 256;
    const bf16_t* srcK0 = Kh + (size_t)(idk0 >> 4) * 128 + (idk0 & 15) * 8;
    const bf16_t* srcK1 = Kh + (size_t)(idk1 >> 4) * 128 + (idk1 & 15) * 8;
    const int offK0 = (idk0 >> 4) * KLSTR + (idk0 & 15) * 8;
    const int offK1 = (idk1 >> 4) * KLSTR + (idk1 & 15) * 8;
    const bf16_t* srcD[4];
    int offD[4];
#pragma unroll
    for (int i = 0; i < 4; i++) {
        const int id = tid + i * 256;
        const int r = id >> 3, sg = id & 7;
        srcD[i] = DTh + (size_t)r * 2048
                      + (sg < 4 ? sg * 8 : 1024 + (sg - 4) * 8);
        offD[i] = (sg < 4) ? r * DLSTR + sg * 8
                           : r * DLSTR + 32 + (sg - 4) * 8;
    }
    // prologue: chunk 0 -> regs -> buf0
    bf16x8 kr0 = *(const bf16x8*)srcK0;
    bf16x8 kr1 = *(const bf16x8*)srcK1;
    bf16x8 dr[4];
#pragma unroll
    for (int i = 0; i < 4; i++) dr[i] = *(const bf16x8*)srcD[i];
    *(bf16x8*)&Ks[0][offK0] = kr0;
    *(bf16x8*)&Ks[0][offK1] = kr1;
#pragma unroll
    for (int i = 0; i < 4; i++) *(bf16x8*)&Ds[0][offD[i]] = dr[i];
    __syncthreads();

    f32x4 acc[8][2];                 // [d-tile][t-tile]
#pragma unroll
    for (int i = 0; i < 8; i++)
#pragma unroll
        for (int j = 0; j < 2; j++) acc[i][j] = (f32x4)0.f;
    float rs[2] = {0.f, 0.f};

    // shfl source lanes for the P layout transform (verified r6)
    const int srcA = (((qd & 1) * 2)     << 4) | l15;
    const int srcB = (((qd & 1) * 2 + 1) << 4) | l15;
    const bool loQuad = (qd < 2);

#pragma unroll 1
    for (int ch = 0; ch < 32; ch++) {
        const int cur = ch & 1;
        if (ch < 31) {                // prefetch next chunk under compute
            kr0 = *(const bf16x8*)(srcK0 + (size_t)(ch + 1) * 4096);
            kr1 = *(const bf16x8*)(srcK1 + (size_t)(ch + 1) * 4096);
#pragma unroll
            for (int i = 0; i < 4; i++)
                dr[i] = *(const bf16x8*)(srcD[i] + (size_t)(ch + 1) * 32);
        }
        // ---- K A-fragments from LDS (lane m=s=si*16+l15, k=dk)
        bf16x8 kfh[2][2], kfl[2][2];   // [si][ks]
#pragma unroll
        for (int si = 0; si < 2; si++) {
            const int row = (si*16 + l15) * KLSTR;
#pragma unroll
            for (int ks = 0; ks < 2; ks++) {
                kfh[si][ks] = ld8(&Ks[cur][row + ks*32 + qd*8]);
                kfl[si][ks] = ld8(&Ks[cur][row + 64 + ks*32 + qd*8]);
            }
        }
        // ---- scores^T: C[m=s][n=t]
        f32x4 pacc[2][2];              // [si][tj]
#pragma unroll
        for (int si = 0; si < 2; si++)
#pragma unroll
            for (int tj = 0; tj < 2; tj++) pacc[si][tj] = (f32x4)0.f;
#pragma unroll
        for (int ks = 0; ks < 2; ks++)
#pragma unroll
            for (int si = 0; si < 2; si++)
#pragma unroll
                for (int tj = 0; tj < 2; tj++) {
                    pacc[si][tj] = __builtin_amdgcn_mfma_f32_16x16x32_bf16(
                        kfh[si][ks], qfh[tj][ks], pacc[si][tj], 0, 0, 0);
                    pacc[si][tj] = __builtin_amdgcn_mfma_f32_16x16x32_bf16(
                        kfl[si][ks], qfh[tj][ks], pacc[si][tj], 0, 0, 0);
                    pacc[si][tj] = __builtin_amdgcn_mfma_f32_16x16x32_bf16(
                        kfh[si][ks], qfl[tj][ks], pacc[si][tj], 0, 0, 0);
                }
        // ---- exp + split + pack (lane holds s = si*16 + qd*4 + r for t=l15)
        unsigned pk01h[2][2], pk23h[2][2], pk01l[2][2], pk23l[2][2]; // [si][tj]
#pragma unroll
        for (int si = 0; si < 2; si++)
#pragma unroll
            for (int tj = 0; tj < 2; tj++) {
                float e0 = __expf(pacc[si][tj][0] * 0.125f);
                float e1 = __expf(pacc[si][tj][1] * 0.125f);
                float e2 = __expf(pacc[si][tj][2] * 0.125f);
                float e3 = __expf(pacc[si][tj][3] * 0.125f);
                rs[tj] += (e0 + e1) + (e2 + e3);
                bf16_t h0=(bf16_t)e0, h1=(bf16_t)e1, h2=(bf16_t)e2, h3=(bf16_t)e3;
                pk01h[si][tj] = pk2(h0, h1);
                pk23h[si][tj] = pk2(h2, h3);
                pk01l[si][tj] = pk2((bf16_t)(e0-(float)h0), (bf16_t)(e1-(float)h1));
                pk23l[si][tj] = pk2((bf16_t)(e2-(float)h2), (bf16_t)(e3-(float)h3));
            }
        // ---- P -> B-operand fragments via shfl (dest: n=t=l15, k=s=qd*8+j)
        bf16x8 pfh[2], pfl[2];
#pragma unroll
        for (int tj = 0; tj < 2; tj++) {
            union { bf16x8 v; unsigned u[4]; } H, L;
            unsigned a0 = __shfl((int)pk01h[0][tj], srcA, 64);
            unsigned a1 = __shfl((int)pk23h[0][tj], srcA, 64);
            unsigned a2 = __shfl((int)pk01h[0][tj], srcB, 64);
            unsigned a3 = __shfl((int)pk23h[0][tj], srcB, 64);
            unsigned b0 = __shfl((int)pk01h[1][tj], srcA, 64);
            unsigned b1 = __shfl((int)pk23h[1][tj], srcA, 64);
            unsigned b2 = __shfl((int)pk01h[1][tj], srcB, 64);
            unsigned b3 = __shfl((int)pk23h[1][tj], srcB, 64);
            H.u[0] = loQuad ? a0 : b0;  H.u[1] = loQuad ? a1 : b1;
            H.u[2] = loQuad ? a2 : b2;  H.u[3] = loQuad ? a3 : b3;
            unsigned c0 = __shfl((int)pk01l[0][tj], srcA, 64);
            unsigned c1 = __shfl((int)pk23l[0][tj], srcA, 64);
            unsigned c2 = __shfl((int)pk01l[0][tj], srcB, 64);
            unsigned c3 = __shfl((int)pk23l[0][tj], srcB, 64);
            unsigned d0_ = __shfl((int)pk01l[1][tj], srcA, 64);
            unsigned d1 = __shfl((int)pk23l[1][tj], srcA, 64);
            unsigned d2 = __shfl((int)pk01l[1][tj], srcB, 64);
            unsigned d3 = __shfl((int)pk23l[1][tj], srcB, 64);
            L.u[0] = loQuad ? c0 : d0_; L.u[1] = loQuad ? c1 : d1;
            L.u[2] = loQuad ? c2 : d2;  L.u[3] = loQuad ? c3 : d3;
            pfh[tj] = H.v; pfl[tj] = L.v;
        }
        // ---- main: acc[d][t] += D x P  (D A-frags from LDS, 2 halves)
#pragma unroll
        for (int half = 0; half < 2; half++) {
            bf16x8 dfh[4], dfl[4];
#pragma unroll
            for (int i = 0; i < 4; i++) {
                const int row = ((half*4 + i)*16 + l15) * DLSTR;
                dfh[i] = ld8(&Ds[cur][row + qd*8]);
                dfl[i] = ld8(&Ds[cur][row + 32 + qd*8]);
            }
#pragma unroll
            for (int i = 0; i < 4; i++)
#pragma unroll
                for (int tj = 0; tj < 2; tj++) {
                    acc[half*4+i][tj] = __builtin_amdgcn_mfma_f32_16x16x32_bf16(
                        dfh[i], pfh[tj], acc[half*4+i][tj], 0, 0, 0);
                    acc[half*4+i][tj] = __builtin_amdgcn_mfma_f32_16x16x32_bf16(
                        dfh[i], pfl[tj], acc[half*4+i][tj], 0, 0, 0);
                    acc[half*4+i][tj] = __builtin_amdgcn_mfma_f32_16x16x32_bf16(
                        dfl[i], pfh[tj], acc[half*4+i][tj], 0, 0, 0);
                }
        }
        // ---- write next chunk to the other buffer, single barrier
        if (ch < 31) {
            *(bf16x8*)&Ks[cur^1][offK0] = kr0;
            *(bf16x8*)&Ks[cur^1][offK1] = kr1;
#pragma unroll
            for (int i = 0; i < 4; i++) *(bf16x8*)&Ds[cur^1][offD[i]] = dr[i];
            __syncthreads();
        }
    }

    // ---- finalize row sums: reduce across quads (lane bits 4,5)
#pragma unroll
    for (int tj = 0; tj < 2; tj++) {
        rs[tj] += __shfl_xor(rs[tj], 16);
        rs[tj] += __shfl_xor(rs[tj], 32);
    }

    const float lam = 1.f / (1.f + __expf(-llam[0]));
    const float oml = 1.f - lam;
    bf16_t* DToutg = (FINAL ? (bf16_t*)nullptr : DTout + (size_t)bh * TDS);

#pragma unroll
    for (int tj = 0; tj < 2; tj++) {
        const int t = Tw + tj*16 + l15;          // C col (global t)
        const float s = lam / rs[tj];
#pragma unroll
        for (int it = 0; it < 8; it++) {
            const int d0 = it*16 + qd*4;         // C rows d0..d0+3
            float v[4];
#pragma unroll
            for (int r = 0; r < 4; r++) {
                const size_t ro = (size_t)(d0 + r)*2048 + t;
                float res = (float)DTh[ro] + (float)DTh[ro + 1024];
                v[r] = oml*res + s*acc[it][tj][r];
            }
            if (FINAL) {
                *(float4*)&Dc[((size_t)bh*Tc + t)*128 + d0] =
                    make_float4(v[0], v[1], v[2], v[3]);
            } else {
#pragma unroll
                for (int r = 0; r < 4; r++) {
                    const size_t ro = (size_t)(d0 + r)*2048 + t;
                    bf16_t h = (bf16_t)v[r];
                    DToutg[ro]        = h;
                    DToutg[ro + 1024] = (bf16_t)(v[r] - (float)h);
                }
            }
        }
    }
}

// ---------------------------------------------------------------------------
// mean over T, two-stage for full-GPU occupancy
// ---------------------------------------------------------------------------
__global__ __launch_bounds__(256)
void mean1_k(const float* __restrict__ D,
             float* __restrict__ M1re, float* __restrict__ M1im)
{
    __shared__ float sre[4][64], sim[4][64];
    const int bh = blockIdx.x, y = blockIdx.y;
    const int d = threadIdx.x & 63, q = threadIdx.x >> 6;
    const float* p = D + (size_t)bh * TD2;
    float ar = 0.f, ai = 0.f;
    const int t0 = y*128 + q*32;
    for (int t = t0; t < t0 + 32; t++) {
        ar += p[t*128 + d]; ai += p[t*128 + 64 + d];
    }
    sre[q][d] = ar; sim[q][d] = ai;
    __syncthreads();
    if (threadIdx.x < 64) {
        M1re[(bh*8 + y)*64 + d] = sre[0][d]+sre[1][d]+sre[2][d]+sre[3][d];
        M1im[(bh*8 + y)*64 + d] = sim[0][d]+sim[1][d]+sim[2][d]+sim[3][d];
    }
}

__global__ __launch_bounds__(64)
void mean2_k(const float* __restrict__ M1re, const float* __restrict__ M1im,
             float* __restrict__ Mre, float* __restrict__ Mim)
{
    const int bh = blockIdx.x, d = threadIdx.x;
    float r = 0.f, im = 0.f;
    for (int y = 0; y < 8; y++) {
        r  += M1re[(bh*8 + y)*64 + d];
        im += M1im[(bh*8 + y)*64 + d];
    }
    Mre[bh*64 + d] = r  * (1.f/1024.f);
    Mim[bh*64 + d] = im * (1.f/1024.f);
}

// ---------------------------------------------------------------------------
// gate softmax over T, two-stage (partial denominators, then normalize+emit)
// ---------------------------------------------------------------------------
__global__ __launch_bounds__(256)
void gate1_k(const float* __restrict__ D,
             const float* __restrict__ Mre, const float* __restrict__ Mim,
             float* __restrict__ Gp)
{
    __shared__ float part[4][64];
    const int bh = blockIdx.x, y = blockIdx.y;
    const int d = threadIdx.x & 63, q = threadIdx.x >> 6;
    const float* p = D + (size_t)bh * TD2;
    const float mre = Mre[bh*64 + d], mim = Mim[bh*64 + d];
    const float mabs = sqrtf(mre*mre + mim*mim);

    float ps = 0.f;
    const int t0 = y*128 + q*32;
    for (int t = t0; t < t0 + 32; t++) {
        float dr = p[t*128 + d], dv = p[t*128 + 64 + d];
        float c = (dr*mre + dv*mim) / (sqrtf(dr*dr + dv*dv)*mabs + 1e-8f);
        ps += __expf(c);
    }
    part[q][d] = ps;
    __syncthreads();
    if (threadIdx.x < 64)
        Gp[(bh*8 + y)*64 + d] = part[0][d]+part[1][d]+part[2][d]+part[3][d];
}

__global__ __launch_bounds__(256)
void gate2_k(const float* __restrict__ D,
             const float* __restrict__ Mre, const float* __restrict__ Mim,
             const float* __restrict__ V, const float* __restrict__ Gp,
             float* __restrict__ gate_out,
             bf16_t* __restrict__ gVh, bf16_t* __restrict__ gVl)
{
    __shared__ float dinv[64];
    const int bh = blockIdx.x, y = blockIdx.y;
    const int d = threadIdx.x & 63, q = threadIdx.x >> 6;
    if (threadIdx.x < 64) {
        float s = 0.f;
        for (int yy = 0; yy < 8; yy++) s += Gp[(bh*8 + yy)*64 + d];
        dinv[d] = 1.f / s;
    }
    __syncthreads();

    const float* p = D + (size_t)bh * TD2;
    const float mre = Mre[bh*64 + d], mim = Mim[bh*64 + d];
    const float mabs = sqrtf(mre*mre + mim*mim);
    const float di_ = dinv[d];
    const int b = bh >> 4, hh = bh & 15;
    const float* pv = V + (size_t)bh * TD;
    const int t0 = y*128 + q*32;
    for (int t = t0; t < t0 + 32; t++) {
        float dr = p[t*128 + d], dv = p[t*128 + 64 + d];
        float c = (dr*mre + dv*mim) / (sqrtf(dr*dr + dv*dv)*mabs + 1e-8f);
        float g = __expf(c) * di_;
        gate_out[(size_t)bh*TD + t*64 + d] = g;
        float gv = g * pv[t*64 + d];
        size_t o = ((size_t)b*Tc + t)*DMc + hh*64 + d;
        bf16_t gh = (bf16_t)gv;
        gVh[o] = gh;
        gVl[o] = (bf16_t)(gv - (float)gh);
    }
}

// ---------------------------------------------------------------------------
extern "C" void kernel_launch(void* const* d_in, const int* in_sizes, int n_in,
                              void* d_out, int out_size, void* d_ws, size_t ws_size,
                              hipStream_t stream)
{
    const float* x    = (const float*)d_in[0];
    const float* W_Q  = (const float*)d_in[1];
    const float* W_K  = (const float*)d_in[2];
    const float* W_re = (const float*)d_in[3];
    const float* W_im = (const float*)d_in[4];
    const float* W_V  = (const float*)d_in[5];
    const float* W_O  = (const float*)d_in[6];
    const float* llam = (const float*)d_in[7];

    float* out      = (float*)d_out;
    float* gate_out = out + (size_t)Mc * DMc;

    float* ws = (float*)d_ws;
    const size_t M1 = 1024*1024;
    float*  Dc  = ws;                          // 32 MB — aliases DT1
    bf16_t* DT1 = (bf16_t*)ws;                 // 16M bf16
    bf16_t* DT0 = (bf16_t*)(ws + 8*M1);        // 16M bf16 (32 MB)
    float*  V   = ws + 16*M1;                  // 16 MB
    bf16_t* Qs  = (bf16_t*)(ws + 20*M1);       // 16 MB
    bf16_t* Ksb = (bf16_t*)(ws + 24*M1);       // 16 MB
    float*  Mre = ws + 28*M1;
    float*  Mim = Mre + 4096;
    bf16_t* xh  = (bf16_t*)(ws + 28*M1 + 8192);// 8 MB
    bf16_t* xl  = xh + 4*M1;                   // 8 MB
    bf16_t* WT  = xl + 4*M1;                   // 24 MB
    bf16_t* gVh = xh;                          // alias: x dead after mgemm<0>
    bf16_t* gVl = xl;
    // scratch for mean/gate two-stage: Ksb region (dead after prop_k)
    float* Gp   = ws + 24*M1;                  // 64*8*64 f32
    float* M1re = Gp + 32768;
    float* M1im = M1re + 32768;
    // K-slice partials for mgemm<1>: CONTIGUOUS 16M f32 at ws+8M1, spanning
    // DT0 (8..16), V (16..20, dead after gate2_k), Qs (20..24, dead after prop).
    float* P0 = ws + 8*M1;
    float* P1 = ws + 12*M1;
    float* P2 = ws + 16*M1;
    float* P3 = ws + 20*M1;

    convx_k<<<4096, 256, 0, stream>>>(x, xh, xl);
    convw_k<<<dim3(32, 32, 6), 256, 0, stream>>>(
        W_Q, W_K, W_re, W_im, W_V, W_O, WT);

    // projections: Q,K -> split slabs; Dre/Dim -> DT0 (transposed split); V f32
    mgemm_k<0><<<dim3(32, 40), 256, 0, stream>>>(
        xh, xl, WT, Qs, Ksb, DT0, V, nullptr);

    prop_k<0><<<dim3(64, 8), 256, 0, stream>>>(Qs, Ksb, DT0, DT1, nullptr, llam);
    prop_k<0><<<dim3(64, 8), 256, 0, stream>>>(Qs, Ksb, DT1, DT0, nullptr, llam);
    prop_k<1><<<dim3(64, 8), 256, 0, stream>>>(Qs, Ksb, DT0, nullptr, Dc, llam);

    mean1_k<<<dim3(64, 8), 256, 0, stream>>>(Dc, M1re, M1im);
    mean2_k<<<64, 64, 0, stream>>>(M1re, M1im, Mre, Mim);
    gate1_k<<<dim3(64, 8), 256, 0, stream>>>(Dc, Mre, Mim, Gp);
    gate2_k<<<dim3(64, 8), 256, 0, stream>>>(Dc, Mre, Mim, V, Gp,
                                             gate_out, gVh, gVl);

    // out = gateV @ W_O, K-split x4 into contiguous partials, then reduce
    mgemm_k<1><<<dim3(32, 8, 4), 256, 0, stream>>>(
        gVh, gVl, WT, nullptr, nullptr, nullptr, nullptr, P0);
    reduce4_k<<<4096, 256, 0, stream>>>(P0, P1, P2, P3, out);
}

// Round 10
// 631.055 us; speedup vs baseline: 1.0519x; 1.0519x over previous
//
#include <hip/hip_runtime.h>
#include <math.h>

// Problem constants
#define Bc 4
#define Tc 1024
#define DMc 1024
#define Hc 16
#define DKc 64
#define BHc 64          // B*H
#define Mc 4096         // B*T
#define TD (Tc*DKc)     // 65536 el per (b,h) slab, stride-64 layout
#define TD2 (Tc*128)    // combined re|im slab, stride-128 layout
#define TDS (128*2048)  // split-D slab: [d(128)][s hi 1024 | s lo 1024] bf16

typedef __bf16 bf16_t;
typedef bf16_t bf16x4 __attribute__((ext_vector_type(4)));
typedef bf16_t bf16x8 __attribute__((ext_vector_type(8)));
typedef float  f32x4  __attribute__((ext_vector_type(4)));
typedef unsigned u32x2 __attribute__((ext_vector_type(2)));

#define KLSTR 136  // prop: K tile row stride (bf16): [hi 64|lo 64|pad 8] — 272B, 16B-aligned rows
#define DLSTR 72   // prop: D tile row stride (bf16): [hi 32|lo 32|pad 8] — 144B, 16B-aligned rows
#define PSTR2 40   // prop: P scratch row stride (bf16): 80B, 16B-aligned rows

__device__ __forceinline__ bf16x8 ld8(const bf16_t* p) {
    return *(const bf16x8*)p;   // ds_read_b128 (all call sites 16B-aligned)
}
__device__ __forceinline__ void st2(bf16_t* p, unsigned a, unsigned b) {
    u32x2 w; w[0] = a; w[1] = b;
    *(u32x2*)p = w;             // ds_write_b64 (8B-aligned call sites)
}
__device__ __forceinline__ void packsplit4(bf16_t* dh, bf16_t* dl, float4 v) {
    bf16x4 h, l;
    h[0]=(bf16_t)v.x; l[0]=(bf16_t)(v.x-(float)h[0]);
    h[1]=(bf16_t)v.y; l[1]=(bf16_t)(v.y-(float)h[1]);
    h[2]=(bf16_t)v.z; l[2]=(bf16_t)(v.z-(float)h[2]);
    h[3]=(bf16_t)v.w; l[3]=(bf16_t)(v.w-(float)h[3]);
    *(bf16x4*)dh = h; *(bf16x4*)dl = l;
}
__device__ __forceinline__ unsigned pk2(bf16_t a, bf16_t b) {
    unsigned short ua = __builtin_bit_cast(unsigned short, a);
    unsigned short ub = __builtin_bit_cast(unsigned short, b);
    return (unsigned)ua | ((unsigned)ub << 16);
}
// async global->LDS, 16B per lane; lds dest must be wave-uniform base.
__device__ __forceinline__ void gload16(const bf16_t* g, bf16_t* l) {
    __builtin_amdgcn_global_load_lds(
        (__attribute__((address_space(1))) void*)(bf16_t*)g,
        (__attribute__((address_space(3))) void*)l, 16, 0, 0);
}

// ---------------------------------------------------------------------------
// Convert x (4096x1024 f32) -> xh, xl bf16
// ---------------------------------------------------------------------------
__global__ __launch_bounds__(256)
void convx_k(const float* __restrict__ x,
             bf16_t* __restrict__ xh, bf16_t* __restrict__ xl)
{
    size_t i = ((size_t)blockIdx.x * 256 + threadIdx.x) * 4;
    float4 v = *(const float4*)&x[i];
    packsplit4(&xh[i], &xl[i], v);
}

// ---------------------------------------------------------------------------
// Convert + transpose each W (1024x1024 f32 [k][n]) -> WT hi/lo bf16 [n][k].
// ---------------------------------------------------------------------------
__global__ __launch_bounds__(256)
void convw_k(const float* __restrict__ W0, const float* __restrict__ W1,
             const float* __restrict__ W2, const float* __restrict__ W3,
             const float* __restrict__ W4, const float* __restrict__ W5,
             bf16_t* __restrict__ WT)
{
    __shared__ float tile[32][33];
    const float* Ws[6] = {W0, W1, W2, W3, W4, W5};
    const int wi = blockIdx.z;
    const float* W = Ws[wi];
    bf16_t* WTh = WT + (size_t)wi * 2097152;
    bf16_t* WTl = WTh + 1048576;

    const int tx = threadIdx.x & 31, ty = threadIdx.x >> 5;
    const int k0 = blockIdx.x * 32, n0 = blockIdx.y * 32;
#pragma unroll
    for (int i = 0; i < 4; i++)
        tile[ty + 8*i][tx] = W[(size_t)(k0 + ty + 8*i) * DMc + n0 + tx];
    __syncthreads();
    const int kg = threadIdx.x & 7, n = threadIdx.x >> 3;
    float4 v = make_float4(tile[kg*4+0][n], tile[kg*4+1][n],
                           tile[kg*4+2][n], tile[kg*4+3][n]);
    const size_t o = (size_t)(n0 + n) * DMc + k0 + kg*4;
    packsplit4(&WTh[o], &WTl[o], v);
}

// ---------------------------------------------------------------------------
// Split-bf16 MFMA GEMM (3 products, f32 accum). A [m][k] hi/lo; B = WT [n][k].
// Staging via global_load_lds width=16 into linear [128][32] LDS tiles.
// ---------------------------------------------------------------------------
template<int MODE>
__global__ __launch_bounds__(256)
void mgemm_k(const bf16_t* __restrict__ Ah, const bf16_t* __restrict__ Al,
             const bf16_t* __restrict__ WT,
             bf16_t* __restrict__ Oq, bf16_t* __restrict__ Ok,
             bf16_t* __restrict__ Od, float* __restrict__ Ov,
             float* __restrict__ Of)
{
    __shared__ bf16_t S[4][128*32];   // 32 KB: Ash, Asl, Bsh, Bsl (linear)

    const int tid = threadIdx.x;
    const int wv  = tid >> 6;
    const int ln  = tid & 63;
    const int l15 = ln & 15;
    const int qd  = ln >> 4;
    const int m0  = blockIdx.x * 128;
    const int by  = blockIdx.y;

    const bf16_t *Bh, *Bl;
    int n0, sel, kt0, kt1;
    float* Opart;
    if (MODE == 0) {
        sel = by >> 3;
        n0 = (by & 7) * 128;
        Bh = WT + (size_t)sel * 2097152;
        Bl = Bh + 1048576;
        kt0 = 0; kt1 = DMc;
        Opart = nullptr;
    } else {
        sel = 5;
        Bh = WT + (size_t)5 * 2097152;
        Bl = Bh + 1048576;
        n0 = by * 128;
        kt0 = blockIdx.z * 256; kt1 = kt0 + 256;
        Opart = Of + (size_t)blockIdx.z * ((size_t)Mc * DMc);
    }

    // staging geometry: per instr i (0..7), lane ln covers LDS elements
    // [i*512 + ln*8, +8)  ->  row = i*16 + (ln>>2), col = (ln&3)*8
    const int srow = ln >> 2;
    const int scol = (ln & 3) * 8;
    const bf16_t* sbase;
    if (wv == 0)      sbase = Ah + (size_t)(m0 + srow) * DMc + scol;
    else if (wv == 1) sbase = Al + (size_t)(m0 + srow) * DMc + scol;
    else if (wv == 2) sbase = Bh + (size_t)(n0 + srow) * DMc + scol;
    else              sbase = Bl + (size_t)(n0 + srow) * DMc + scol;
    sbase += kt0;
    bf16_t* ldst = &S[wv][0];

    f32x4 acc[4][4];
#pragma unroll
    for (int i = 0; i < 4; i++)
#pragma unroll
        for (int j = 0; j < 4; j++) acc[i][j] = (f32x4)0.f;

#pragma unroll 1
    for (int kt = kt0; kt < kt1; kt += 32) {
        __syncthreads();   // previous tile fully consumed
#pragma unroll
        for (int i = 0; i < 8; i++)
            gload16(sbase + (size_t)i * 16 * DMc, ldst + i * 512);
        sbase += 32;
        __syncthreads();   // vmcnt drained before barrier -> tile visible

        bf16x8 fah[4], fal[4], fbh[4], fbl[4];
#pragma unroll
        for (int it = 0; it < 4; it++) {
            const int row = ((wv>>1)*64 + it*16 + l15) * 32 + qd*8;
            fah[it] = *(const bf16x8*)&S[0][row];
            fal[it] = *(const bf16x8*)&S[1][row];
        }
#pragma unroll
        for (int jt = 0; jt < 4; jt++) {
            const int row = ((wv&1)*64 + jt*16 + l15) * 32 + qd*8;
            fbh[jt] = *(const bf16x8*)&S[2][row];
            fbl[jt] = *(const bf16x8*)&S[3][row];
        }
#pragma unroll
        for (int it = 0; it < 4; it++)
#pragma unroll
            for (int jt = 0; jt < 4; jt++) {
                acc[it][jt] = __builtin_amdgcn_mfma_f32_16x16x32_bf16(
                    fah[it], fbh[jt], acc[it][jt], 0, 0, 0);
                acc[it][jt] = __builtin_amdgcn_mfma_f32_16x16x32_bf16(
                    fah[it], fbl[jt], acc[it][jt], 0, 0, 0);
                acc[it][jt] = __builtin_amdgcn_mfma_f32_16x16x32_bf16(
                    fal[it], fbh[jt], acc[it][jt], 0, 0, 0);
            }
    }

#pragma unroll
    for (int it = 0; it < 4; it++) {
        const int mb = m0 + (wv>>1)*64 + it*16 + qd*4;
#pragma unroll
        for (int jt = 0; jt < 4; jt++) {
            const int col = n0 + (wv&1)*64 + jt*16 + l15;
            if (MODE == 0) {
                const int hh = col >> 6;
                const int b  = mb >> 10, t0 = mb & 1023;
                if (sel <= 1) {
                    bf16_t* O = sel ? Ok : Oq;
                    const int d = col & 63;
#pragma unroll
                    for (int r = 0; r < 4; r++) {
                        const float val = acc[it][jt][r];
                        const size_t o = ((size_t)(b*Hc + hh)*Tc + t0 + r)*128 + d;
                        bf16_t vh = (bf16_t)val;
                        O[o]      = vh;
                        O[o + 64] = (bf16_t)(val - (float)vh);
                    }
                } else if (sel <= 3) {
                    // transposed split-D: [bh][d][t hi | t lo]
                    const int d = (sel == 3 ? 64 : 0) + (col & 63);
                    bf16x4 h4, l4;
#pragma unroll
                    for (int r = 0; r < 4; r++) {
                        const float val = acc[it][jt][r];
                        h4[r] = (bf16_t)val;
                        l4[r] = (bf16_t)(val - (float)h4[r]);
                    }
                    const size_t o = (size_t)(b*Hc + hh)*TDS + (size_t)d*2048 + t0;
                    *(bf16x4*)&Od[o]        = h4;
                    *(bf16x4*)&Od[o + 1024] = l4;
                } else {
#pragma unroll
                    for (int r = 0; r < 4; r++)
                        Ov[((size_t)(b*Hc + hh)*Tc + t0 + r)*64 + (col & 63)]
                            = acc[it][jt][r];
                }
            } else {
#pragma unroll
                for (int r = 0; r < 4; r++)
                    Opart[(size_t)(mb + r) * DMc + col] = acc[it][jt][r];
            }
        }
    }
}

// ---------------------------------------------------------------------------
// Sum 4 K-slice partials -> out
// ---------------------------------------------------------------------------
__global__ __launch_bounds__(256)
void reduce4_k(const float* __restrict__ p0, const float* __restrict__ p1,
               const float* __restrict__ p2, const float* __restrict__ p3,
               float* __restrict__ out)
{
    size_t i = ((size_t)blockIdx.x * 256 + threadIdx.x) * 4;
    float4 a = *(const float4*)&p0[i];
    float4 b = *(const float4*)&p1[i];
    float4 c = *(const float4*)&p2[i];
    float4 d = *(const float4*)&p3[i];
    *(float4*)&out[i] = make_float4(a.x+b.x+c.x+d.x, a.y+b.y+c.y+d.y,
                                    a.z+b.z+c.z+d.z, a.w+b.w+c.w+d.w);
}

// ---------------------------------------------------------------------------
// Fused propagation step (r5 structure exactly; measured-best config:
// 256 threads, grid (64,8), 2 blocks/CU, 2 barriers/chunk, T14 prefetch)
// with ONE change: the P layout transform (scores C[s][t] -> B-operand
// fragments) goes through a WAVE-PRIVATE LDS scratch (write [t][s] pairs,
// read back b128 rows) instead of 32 ds_bpermute + 32 cndmask.  Mapping
// re-derived against the verified shfl semantics: read row l15 cols
// qd*8..+7 <- writes at col si*16+qd'*4 (hi/lo), identical pfh/pfl values
// -> bitwise-same output.  No barrier needed (same-wave RAW via lgkmcnt).
// ---------------------------------------------------------------------------
template<int FINAL>
__global__ __launch_bounds__(256)
void prop_k(const bf16_t* __restrict__ Qg, const bf16_t* __restrict__ Kg,
            const bf16_t* __restrict__ DTin, bf16_t* __restrict__ DTout,
            float* __restrict__ Dc, const float* __restrict__ llam)
{
    __shared__ bf16_t Ks[32*KLSTR];        // 8.7 KB
    __shared__ bf16_t Ds[128*DLSTR];       // 18.4 KB
    __shared__ bf16_t Pbh[4][2][16*PSTR2]; // 10.25 KB wave-private P hi
    __shared__ bf16_t Pbl[4][2][16*PSTR2]; // 10.25 KB wave-private P lo

    const int tid = threadIdx.x;
    const int wv  = tid >> 6;
    const int ln  = tid & 63;
    const int l15 = ln & 15;
    const int qd  = ln >> 4;
    const int bh  = blockIdx.x;
    const int Tw  = blockIdx.y * 128 + wv * 32;   // this wave's 32 t's

    const bf16_t* Qh  = Qg   + (size_t)bh * (Tc*128);
    const bf16_t* Kh  = Kg   + (size_t)bh * (Tc*128);
    const bf16_t* DTh = DTin + (size_t)bh * TDS;

    // Q B-fragments (lane n=t=l15, k=dk=qd*8+j), loop-invariant
    bf16x8 qfh[2][2], qfl[2][2];     // [tj][ks]
#pragma unroll
    for (int tj = 0; tj < 2; tj++) {
        const bf16_t* qp = &Qh[(size_t)(Tw + tj*16 + l15) * 128];
#pragma unroll
        for (int ks = 0; ks < 2; ks++) {
            qfh[tj][ks] = *(const bf16x8*)&qp[ks*32 + qd*8];
            qfl[tj][ks] = *(const bf16x8*)&qp[64 + ks*32 + qd*8];
        }
    }

    // T14 staging geometry (loop-invariant per-thread src/dst)
    const int idk0 = tid, idk1 = tid + 256;
    const bf16_t* srcK0 = Kh + (size_t)(idk0 >> 4) * 128 + (idk0 & 15) * 8;
    const bf16_t* srcK1 = Kh + (size_t)(idk1 >> 4) * 128 + (idk1 & 15) * 8;
    bf16_t* dstK0 = &Ks[(idk0 >> 4) * KLSTR + (idk0 & 15) * 8];
    bf16_t* dstK1 = &Ks[(idk1 >> 4) * KLSTR + (idk1 & 15) * 8];
    const bf16_t* srcD[4];
    bf16_t* dstD[4];
#pragma unroll
    for (int i = 0; i < 4; i++) {
        const int id = tid + i * 256;
        const int r = id >> 3, sg = id & 7;
        srcD[i] = DTh + (size_t)r * 2048
                      + (sg < 4 ? sg * 8 : 1024 + (sg - 4) * 8);
        dstD[i] = (sg < 4) ? &Ds[r * DLSTR + sg * 8]
                           : &Ds[r * DLSTR + 32 + (sg - 4) * 8];
    }
    // prologue: chunk 0 into regs
    bf16x8 kr0 = *(const bf16x8*)srcK0;
    bf16x8 kr1 = *(const bf16x8*)srcK1;
    bf16x8 dr[4];
#pragma unroll
    for (int i = 0; i < 4; i++) dr[i] = *(const bf16x8*)srcD[i];

    f32x4 acc[8][2];                 // [d-tile][t-tile]
#pragma unroll
    for (int i = 0; i < 8; i++)
#pragma unroll
        for (int j = 0; j < 2; j++) acc[i][j] = (f32x4)0.f;
    float rs[2] = {0.f, 0.f};

#pragma unroll 1
    for (int ch = 0; ch < 32; ch++) {
        __syncthreads();              // prev chunk fully consumed; LDS writable
        *(bf16x8*)dstK0 = kr0;
        *(bf16x8*)dstK1 = kr1;
#pragma unroll
        for (int i = 0; i < 4; i++) *(bf16x8*)dstD[i] = dr[i];
        __syncthreads();              // staged data visible
        if (ch < 31) {                // prefetch next chunk under compute
            kr0 = *(const bf16x8*)(srcK0 + (size_t)(ch + 1) * 4096);
            kr1 = *(const bf16x8*)(srcK1 + (size_t)(ch + 1) * 4096);
#pragma unroll
            for (int i = 0; i < 4; i++)
                dr[i] = *(const bf16x8*)(srcD[i] + (size_t)(ch + 1) * 32);
        }
        // ---- K A-fragments from LDS (lane m=s=si*16+l15, k=dk)
        bf16x8 kfh[2][2], kfl[2][2];   // [si][ks]
#pragma unroll
        for (int si = 0; si < 2; si++) {
            const int row = (si*16 + l15) * KLSTR;
#pragma unroll
            for (int ks = 0; ks < 2; ks++) {
                kfh[si][ks] = ld8(&Ks[row + ks*32 + qd*8]);
                kfl[si][ks] = ld8(&Ks[row + 64 + ks*32 + qd*8]);
            }
        }
        // ---- scores^T: C[m=s][n=t]
        f32x4 pacc[2][2];              // [si][tj]
#pragma unroll
        for (int si = 0; si < 2; si++)
#pragma unroll
            for (int tj = 0; tj < 2; tj++) pacc[si][tj] = (f32x4)0.f;
#pragma unroll
        for (int ks = 0; ks < 2; ks++)
#pragma unroll
            for (int si = 0; si < 2; si++)
#pragma unroll
                for (int tj = 0; tj < 2; tj++) {
                    pacc[si][tj] = __builtin_amdgcn_mfma_f32_16x16x32_bf16(
                        kfh[si][ks], qfh[tj][ks], pacc[si][tj], 0, 0, 0);
                    pacc[si][tj] = __builtin_amdgcn_mfma_f32_16x16x32_bf16(
                        kfl[si][ks], qfh[tj][ks], pacc[si][tj], 0, 0, 0);
                    pacc[si][tj] = __builtin_amdgcn_mfma_f32_16x16x32_bf16(
                        kfh[si][ks], qfl[tj][ks], pacc[si][tj], 0, 0, 0);
                }
        // ---- exp + split + pack (lane holds s = si*16 + qd*4 + r for t=l15)
        unsigned pk01h[2][2], pk23h[2][2], pk01l[2][2], pk23l[2][2]; // [si][tj]
#pragma unroll
        for (int si = 0; si < 2; si++)
#pragma unroll
            for (int tj = 0; tj < 2; tj++) {
                float e0 = __expf(pacc[si][tj][0] * 0.125f);
                float e1 = __expf(pacc[si][tj][1] * 0.125f);
                float e2 = __expf(pacc[si][tj][2] * 0.125f);
                float e3 = __expf(pacc[si][tj][3] * 0.125f);
                rs[tj] += (e0 + e1) + (e2 + e3);
                bf16_t h0=(bf16_t)e0, h1=(bf16_t)e1, h2=(bf16_t)e2, h3=(bf16_t)e3;
                pk01h[si][tj] = pk2(h0, h1);
                pk23h[si][tj] = pk2(h2, h3);
                pk01l[si][tj] = pk2((bf16_t)(e0-(float)h0), (bf16_t)(e1-(float)h1));
                pk23l[si][tj] = pk2((bf16_t)(e2-(float)h2), (bf16_t)(e3-(float)h3));
            }
        // ---- P -> B-operand fragments via wave-private LDS [t][s] scratch
        // write: lane(l15,qd) holds s = si*16 + qd*4 + {0..3} for t = l15
        // read:  lane(l15,qd) needs s = qd*8..qd*8+7 for t = l15
        bf16x8 pfh[2], pfl[2];
#pragma unroll
        for (int tj = 0; tj < 2; tj++) {
            bf16_t* ph = &Pbh[wv][tj][0];
            bf16_t* pl = &Pbl[wv][tj][0];
            st2(&ph[l15*PSTR2 + qd*4],      pk01h[0][tj], pk23h[0][tj]);
            st2(&ph[l15*PSTR2 + 16 + qd*4], pk01h[1][tj], pk23h[1][tj]);
            st2(&pl[l15*PSTR2 + qd*4],      pk01l[0][tj], pk23l[0][tj]);
            st2(&pl[l15*PSTR2 + 16 + qd*4], pk01l[1][tj], pk23l[1][tj]);
            pfh[tj] = ld8(&ph[l15*PSTR2 + qd*8]);
            pfl[tj] = ld8(&pl[l15*PSTR2 + qd*8]);
        }
        // ---- main: acc[d][t] += D x P  (D A-frags from LDS, 2 halves)
#pragma unroll
        for (int half = 0; half < 2; half++) {
            bf16x8 dfh[4], dfl[4];
#pragma unroll
            for (int i = 0; i < 4; i++) {
                const int row = ((half*4 + i)*16 + l15) * DLSTR;
                dfh[i] = ld8(&Ds[row + qd*8]);
                dfl[i] = ld8(&Ds[row + 32 + qd*8]);
            }
#pragma unroll
            for (int i = 0; i < 4; i++)
#pragma unroll
                for (int tj = 0; tj < 2; tj++) {
                    acc[half*4+i][tj] = __builtin_amdgcn_mfma_f32_16x16x32_bf16(
                        dfh[i], pfh[tj], acc[half*4+i][tj], 0, 0, 0);
                    acc[half*4+i][tj] = __builtin_amdgcn_mfma_f32_16x16x32_bf16(
                        dfh[i], pfl[tj], acc[half*4+i][tj], 0, 0, 0);
                    acc[half*4+i][tj] = __builtin_amdgcn_mfma_f32_16x16x32_bf16(
                        dfl[i], pfh[tj], acc[half*4+i][tj], 0, 0, 0);
                }
        }
    }

    // ---- finalize row sums: reduce across quads (lane bits 4,5)
#pragma unroll
    for (int tj = 0; tj < 2; tj++) {
        rs[tj] += __shfl_xor(rs[tj], 16);
        rs[tj] += __shfl_xor(rs[tj], 32);
    }

    const float lam = 1.f / (1.f + __expf(-llam[0]));
    const float oml = 1.f - lam;
    bf16_t* DToutg = (FINAL ? (bf16_t*)nullptr : DTout + (size_t)bh * TDS);

#pragma unroll
    for (int tj = 0; tj < 2; tj++) {
        const int t = Tw + tj*16 + l15;          // C col (global t)
        const float s = lam / rs[tj];
#pragma unroll
        for (int it = 0; it < 8; it++) {
            const int d0 = it*16 + qd*4;         // C rows d0..d0+3
            float v[4];
#pragma unroll
            for (int r = 0; r < 4; r++) {
                const size_t ro = (size_t)(d0 + r)*2048 + t;
                float res = (float)DTh[ro] + (float)DTh[ro + 1024];
                v[r] = oml*res + s*acc[it][tj][r];
            }
            if (FINAL) {
                *(float4*)&Dc[((size_t)bh*Tc + t)*128 + d0] =
                    make_float4(v[0], v[1], v[2], v[3]);
            } else {
#pragma unroll
                for (int r = 0; r < 4; r++) {
                    const size_t ro = (size_t)(d0 + r)*2048 + t;
                    bf16_t h = (bf16_t)v[r];
                    DToutg[ro]        = h;
                    DToutg[ro + 1024] = (bf16_t)(v[r] - (float)h);
                }
            }
        }
    }
}

// ---------------------------------------------------------------------------
// mean over T, two-stage for full-GPU occupancy
// ---------------------------------------------------------------------------
__global__ __launch_bounds__(256)
void mean1_k(const float* __restrict__ D,
             float* __restrict__ M1re, float* __restrict__ M1im)
{
    __shared__ float sre[4][64], sim[4][64];
    const int bh = blockIdx.x, y = blockIdx.y;
    const int d = threadIdx.x & 63, q = threadIdx.x >> 6;
    const float* p = D + (size_t)bh * TD2;
    float ar = 0.f, ai = 0.f;
    const int t0 = y*128 + q*32;
    for (int t = t0; t < t0 + 32; t++) {
        ar += p[t*128 + d]; ai += p[t*128 + 64 + d];
    }
    sre[q][d] = ar; sim[q][d] = ai;
    __syncthreads();
    if (threadIdx.x < 64) {
        M1re[(bh*8 + y)*64 + d] = sre[0][d]+sre[1][d]+sre[2][d]+sre[3][d];
        M1im[(bh*8 + y)*64 + d] = sim[0][d]+sim[1][d]+sim[2][d]+sim[3][d];
    }
}

__global__ __launch_bounds__(64)
void mean2_k(const float* __restrict__ M1re, const float* __restrict__ M1im,
             float* __restrict__ Mre, float* __restrict__ Mim)
{
    const int bh = blockIdx.x, d = threadIdx.x;
    float r = 0.f, im = 0.f;
    for (int y = 0; y < 8; y++) {
        r  += M1re[(bh*8 + y)*64 + d];
        im += M1im[(bh*8 + y)*64 + d];
    }
    Mre[bh*64 + d] = r  * (1.f/1024.f);
    Mim[bh*64 + d] = im * (1.f/1024.f);
}

// ---------------------------------------------------------------------------
// gate softmax over T, two-stage (partial denominators, then normalize+emit)
// ---------------------------------------------------------------------------
__global__ __launch_bounds__(256)
void gate1_k(const float* __restrict__ D,
             const float* __restrict__ Mre, const float* __restrict__ Mim,
             float* __restrict__ Gp)
{
    __shared__ float part[4][64];
    const int bh = blockIdx.x, y = blockIdx.y;
    const int d = threadIdx.x & 63, q = threadIdx.x >> 6;
    const float* p = D + (size_t)bh * TD2;
    const float mre = Mre[bh*64 + d], mim = Mim[bh*64 + d];
    const float mabs = sqrtf(mre*mre + mim*mim);

    float ps = 0.f;
    const int t0 = y*128 + q*32;
    for (int t = t0; t < t0 + 32; t++) {
        float dr = p[t*128 + d], dv = p[t*128 + 64 + d];
        float c = (dr*mre + dv*mim) / (sqrtf(dr*dr + dv*dv)*mabs + 1e-8f);
        ps += __expf(c);
    }
    part[q][d] = ps;
    __syncthreads();
    if (threadIdx.x < 64)
        Gp[(bh*8 + y)*64 + d] = part[0][d]+part[1][d]+part[2][d]+part[3][d];
}

__global__ __launch_bounds__(256)
void gate2_k(const float* __restrict__ D,
             const float* __restrict__ Mre, const float* __restrict__ Mim,
             const float* __restrict__ V, const float* __restrict__ Gp,
             float* __restrict__ gate_out,
             bf16_t* __restrict__ gVh, bf16_t* __restrict__ gVl)
{
    __shared__ float dinv[64];
    const int bh = blockIdx.x, y = blockIdx.y;
    const int d = threadIdx.x & 63, q = threadIdx.x >> 6;
    if (threadIdx.x < 64) {
        float s = 0.f;
        for (int yy = 0; yy < 8; yy++) s += Gp[(bh*8 + yy)*64 + d];
        dinv[d] = 1.f / s;
    }
    __syncthreads();

    const float* p = D + (size_t)bh * TD2;
    const float mre = Mre[bh*64 + d], mim = Mim[bh*64 + d];
    const float mabs = sqrtf(mre*mre + mim*mim);
    const float di_ = dinv[d];
    const int b = bh >> 4, hh = bh & 15;
    const float* pv = V + (size_t)bh * TD;
    const int t0 = y*128 + q*32;
    for (int t = t0; t < t0 + 32; t++) {
        float dr = p[t*128 + d], dv = p[t*128 + 64 + d];
        float c = (dr*mre + dv*mim) / (sqrtf(dr*dr + dv*dv)*mabs + 1e-8f);
        float g = __expf(c) * di_;
        gate_out[(size_t)bh*TD + t*64 + d] = g;
        float gv = g * pv[t*64 + d];
        size_t o = ((size_t)b*Tc + t)*DMc + hh*64 + d;
        bf16_t gh = (bf16_t)gv;
        gVh[o] = gh;
        gVl[o] = (bf16_t)(gv - (float)gh);
    }
}

// ---------------------------------------------------------------------------
extern "C" void kernel_launch(void* const* d_in, const int* in_sizes, int n_in,
                              void* d_out, int out_size, void* d_ws, size_t ws_size,
                              hipStream_t stream)
{
    const float* x    = (const float*)d_in[0];
    const float* W_Q  = (const float*)d_in[1];
    const float* W_K  = (const float*)d_in[2];
    const float* W_re = (const float*)d_in[3];
    const float* W_im = (const float*)d_in[4];
    const float* W_V  = (const float*)d_in[5];
    const float* W_O  = (const float*)d_in[6];
    const float* llam = (const float*)d_in[7];

    float* out      = (float*)d_out;
    float* gate_out = out + (size_t)Mc * DMc;

    float* ws = (float*)d_ws;
    const size_t M1 = 1024*1024;
    float*  Dc  = ws;                          // 32 MB — aliases DT1
    bf16_t* DT1 = (bf16_t*)ws;                 // 16M bf16
    bf16_t* DT0 = (bf16_t*)(ws + 8*M1);        // 16M bf16 (32 MB)
    float*  V   = ws + 16*M1;                  // 16 MB
    bf16_t* Qs  = (bf16_t*)(ws + 20*M1);       // 16 MB
    bf16_t* Ksb = (bf16_t*)(ws + 24*M1);       // 16 MB
    float*  Mre = ws + 28*M1;
    float*  Mim = Mre + 4096;
    bf16_t* xh  = (bf16_t*)(ws + 28*M1 + 8192);// 8 MB
    bf16_t* xl  = xh + 4*M1;                   // 8 MB
    bf16_t* WT  = xl + 4*M1;                   // 24 MB
    bf16_t* gVh = xh;                          // alias: x dead after mgemm<0>
    bf16_t* gVl = xl;
    // scratch for mean/gate two-stage: Ksb region (dead after prop_k)
    float* Gp   = ws + 24*M1;                  // 64*8*64 f32
    float* M1re = Gp + 32768;
    float* M1im = M1re + 32768;
    // K-slice partials for mgemm<1>: CONTIGUOUS 16M f32 at ws+8M1, spanning
    // DT0 (8..16), V (16..20, dead after gate2_k), Qs (20..24, dead after prop).
    float* P0 = ws + 8*M1;
    float* P1 = ws + 12*M1;
    float* P2 = ws + 16*M1;
    float* P3 = ws + 20*M1;

    convx_k<<<4096, 256, 0, stream>>>(x, xh, xl);
    convw_k<<<dim3(32, 32, 6), 256, 0, stream>>>(
        W_Q, W_K, W_re, W_im, W_V, W_O, WT);

    // projections: Q,K -> split slabs; Dre/Dim -> DT0 (transposed split); V f32
    mgemm_k<0><<<dim3(32, 40), 256, 0, stream>>>(
        xh, xl, WT, Qs, Ksb, DT0, V, nullptr);

    prop_k<0><<<dim3(64, 8), 256, 0, stream>>>(Qs, Ksb, DT0, DT1, nullptr, llam);
    prop_k<0><<<dim3(64, 8), 256, 0, stream>>>(Qs, Ksb, DT1, DT0, nullptr, llam);
    prop_k<1><<<dim3(64, 8), 256, 0, stream>>>(Qs, Ksb, DT0, nullptr, Dc, llam);

    mean1_k<<<dim3(64, 8), 256, 0, stream>>>(Dc, M1re, M1im);
    mean2_k<<<64, 64, 0, stream>>>(M1re, M1im, Mre, Mim);
    gate1_k<<<dim3(64, 8), 256, 0, stream>>>(Dc, Mre, Mim, Gp);
    gate2_k<<<dim3(64, 8), 256, 0, stream>>>(Dc, Mre, Mim, V, Gp,
                                             gate_out, gVh, gVl);

    // out = gateV @ W_O, K-split x4 into contiguous partials, then reduce
    mgemm_k<1><<<dim3(32, 8, 4), 256, 0, stream>>>(
        gVh, gVl, WT, nullptr, nullptr, nullptr, nullptr, P0);
    reduce4_k<<<4096, 256, 0, stream>>>(P0, P1, P2, P3, out);
}

// Round 11
// 606.246 us; speedup vs baseline: 1.0949x; 1.0409x over previous
//
#include <hip/hip_runtime.h>
#include <math.h>

// Problem constants
#define Bc 4
#define Tc 1024
#define DMc 1024
#define Hc 16
#define DKc 64
#define BHc 64          // B*H
#define Mc 4096         // B*T
#define TD (Tc*DKc)     // 65536 el per (b,h) slab, stride-64 layout
#define TD2 (Tc*128)    // combined re|im slab, stride-128 layout
#define TDS (128*2048)  // split-D slab: [d(128)][s hi 1024 | s lo 1024] bf16

typedef __bf16 bf16_t;
typedef bf16_t bf16x4 __attribute__((ext_vector_type(4)));
typedef bf16_t bf16x8 __attribute__((ext_vector_type(8)));
typedef float  f32x4  __attribute__((ext_vector_type(4)));

#define KLSTR 136  // prop: K tile row stride (bf16): [hi 64|lo 64|pad 8] — 272B, 16B-aligned rows
#define DLSTR 72   // prop: D tile row stride (bf16): [hi 32|lo 32|pad 8] — 144B, 16B-aligned rows

__device__ __forceinline__ bf16x8 ld8(const bf16_t* p) {
    return *(const bf16x8*)p;   // ds_read_b128 (all call sites 16B-aligned)
}
__device__ __forceinline__ void packsplit4(bf16_t* dh, bf16_t* dl, float4 v) {
    bf16x4 h, l;
    h[0]=(bf16_t)v.x; l[0]=(bf16_t)(v.x-(float)h[0]);
    h[1]=(bf16_t)v.y; l[1]=(bf16_t)(v.y-(float)h[1]);
    h[2]=(bf16_t)v.z; l[2]=(bf16_t)(v.z-(float)h[2]);
    h[3]=(bf16_t)v.w; l[3]=(bf16_t)(v.w-(float)h[3]);
    *(bf16x4*)dh = h; *(bf16x4*)dl = l;
}
__device__ __forceinline__ unsigned pk2(bf16_t a, bf16_t b) {
    unsigned short ua = __builtin_bit_cast(unsigned short, a);
    unsigned short ub = __builtin_bit_cast(unsigned short, b);
    return (unsigned)ua | ((unsigned)ub << 16);
}
// async global->LDS, 16B per lane; lds dest must be wave-uniform base.
__device__ __forceinline__ void gload16(const bf16_t* g, bf16_t* l) {
    __builtin_amdgcn_global_load_lds(
        (__attribute__((address_space(1))) void*)(bf16_t*)g,
        (__attribute__((address_space(3))) void*)l, 16, 0, 0);
}

// ---------------------------------------------------------------------------
// Convert x (4096x1024 f32) -> xh, xl bf16
// ---------------------------------------------------------------------------
__global__ __launch_bounds__(256)
void convx_k(const float* __restrict__ x,
             bf16_t* __restrict__ xh, bf16_t* __restrict__ xl)
{
    size_t i = ((size_t)blockIdx.x * 256 + threadIdx.x) * 4;
    float4 v = *(const float4*)&x[i];
    packsplit4(&xh[i], &xl[i], v);
}

// ---------------------------------------------------------------------------
// Convert + transpose each W (1024x1024 f32 [k][n]) -> WT hi/lo bf16 [n][k].
// ---------------------------------------------------------------------------
__global__ __launch_bounds__(256)
void convw_k(const float* __restrict__ W0, const float* __restrict__ W1,
             const float* __restrict__ W2, const float* __restrict__ W3,
             const float* __restrict__ W4, const float* __restrict__ W5,
             bf16_t* __restrict__ WT)
{
    __shared__ float tile[32][33];
    const float* Ws[6] = {W0, W1, W2, W3, W4, W5};
    const int wi = blockIdx.z;
    const float* W = Ws[wi];
    bf16_t* WTh = WT + (size_t)wi * 2097152;
    bf16_t* WTl = WTh + 1048576;

    const int tx = threadIdx.x & 31, ty = threadIdx.x >> 5;
    const int k0 = blockIdx.x * 32, n0 = blockIdx.y * 32;
#pragma unroll
    for (int i = 0; i < 4; i++)
        tile[ty + 8*i][tx] = W[(size_t)(k0 + ty + 8*i) * DMc + n0 + tx];
    __syncthreads();
    const int kg = threadIdx.x & 7, n = threadIdx.x >> 3;
    float4 v = make_float4(tile[kg*4+0][n], tile[kg*4+1][n],
                           tile[kg*4+2][n], tile[kg*4+3][n]);
    const size_t o = (size_t)(n0 + n) * DMc + k0 + kg*4;
    packsplit4(&WTh[o], &WTl[o], v);
}

// ---------------------------------------------------------------------------
// Split-bf16 MFMA GEMM (3 products, f32 accum). A [m][k] hi/lo; B = WT [n][k].
// Staging via global_load_lds width=16 into linear [128][32] LDS tiles.
// MODE 1: K-split x2 (blockIdx.z selects K=512 slice), f32 partials at
// Of + z*4M floats; reduced by reduce2_k.
// ---------------------------------------------------------------------------
template<int MODE>
__global__ __launch_bounds__(256)
void mgemm_k(const bf16_t* __restrict__ Ah, const bf16_t* __restrict__ Al,
             const bf16_t* __restrict__ WT,
             bf16_t* __restrict__ Oq, bf16_t* __restrict__ Ok,
             bf16_t* __restrict__ Od, float* __restrict__ Ov,
             float* __restrict__ Of)
{
    __shared__ bf16_t S[4][128*32];   // 32 KB: Ash, Asl, Bsh, Bsl (linear)

    const int tid = threadIdx.x;
    const int wv  = tid >> 6;
    const int ln  = tid & 63;
    const int l15 = ln & 15;
    const int qd  = ln >> 4;
    const int m0  = blockIdx.x * 128;
    const int by  = blockIdx.y;

    const bf16_t *Bh, *Bl;
    int n0, sel, kt0, kt1;
    float* Opart;
    if (MODE == 0) {
        sel = by >> 3;
        n0 = (by & 7) * 128;
        Bh = WT + (size_t)sel * 2097152;
        Bl = Bh + 1048576;
        kt0 = 0; kt1 = DMc;
        Opart = nullptr;
    } else {
        sel = 5;
        Bh = WT + (size_t)5 * 2097152;
        Bl = Bh + 1048576;
        n0 = by * 128;
        kt0 = blockIdx.z * 512; kt1 = kt0 + 512;
        Opart = Of + (size_t)blockIdx.z * ((size_t)Mc * DMc);
    }

    // staging geometry: per instr i (0..7), lane ln covers LDS elements
    // [i*512 + ln*8, +8)  ->  row = i*16 + (ln>>2), col = (ln&3)*8
    const int srow = ln >> 2;
    const int scol = (ln & 3) * 8;
    const bf16_t* sbase;
    if (wv == 0)      sbase = Ah + (size_t)(m0 + srow) * DMc + scol;
    else if (wv == 1) sbase = Al + (size_t)(m0 + srow) * DMc + scol;
    else if (wv == 2) sbase = Bh + (size_t)(n0 + srow) * DMc + scol;
    else              sbase = Bl + (size_t)(n0 + srow) * DMc + scol;
    sbase += kt0;
    bf16_t* ldst = &S[wv][0];

    f32x4 acc[4][4];
#pragma unroll
    for (int i = 0; i < 4; i++)
#pragma unroll
        for (int j = 0; j < 4; j++) acc[i][j] = (f32x4)0.f;

#pragma unroll 1
    for (int kt = kt0; kt < kt1; kt += 32) {
        __syncthreads();   // previous tile fully consumed
#pragma unroll
        for (int i = 0; i < 8; i++)
            gload16(sbase + (size_t)i * 16 * DMc, ldst + i * 512);
        sbase += 32;
        __syncthreads();   // vmcnt drained before barrier -> tile visible

        bf16x8 fah[4], fal[4], fbh[4], fbl[4];
#pragma unroll
        for (int it = 0; it < 4; it++) {
            const int row = ((wv>>1)*64 + it*16 + l15) * 32 + qd*8;
            fah[it] = *(const bf16x8*)&S[0][row];
            fal[it] = *(const bf16x8*)&S[1][row];
        }
#pragma unroll
        for (int jt = 0; jt < 4; jt++) {
            const int row = ((wv&1)*64 + jt*16 + l15) * 32 + qd*8;
            fbh[jt] = *(const bf16x8*)&S[2][row];
            fbl[jt] = *(const bf16x8*)&S[3][row];
        }
#pragma unroll
        for (int it = 0; it < 4; it++)
#pragma unroll
            for (int jt = 0; jt < 4; jt++) {
                acc[it][jt] = __builtin_amdgcn_mfma_f32_16x16x32_bf16(
                    fah[it], fbh[jt], acc[it][jt], 0, 0, 0);
                acc[it][jt] = __builtin_amdgcn_mfma_f32_16x16x32_bf16(
                    fah[it], fbl[jt], acc[it][jt], 0, 0, 0);
                acc[it][jt] = __builtin_amdgcn_mfma_f32_16x16x32_bf16(
                    fal[it], fbh[jt], acc[it][jt], 0, 0, 0);
            }
    }

#pragma unroll
    for (int it = 0; it < 4; it++) {
        const int mb = m0 + (wv>>1)*64 + it*16 + qd*4;
#pragma unroll
        for (int jt = 0; jt < 4; jt++) {
            const int col = n0 + (wv&1)*64 + jt*16 + l15;
            if (MODE == 0) {
                const int hh = col >> 6;
                const int b  = mb >> 10, t0 = mb & 1023;
                if (sel <= 1) {
                    bf16_t* O = sel ? Ok : Oq;
                    const int d = col & 63;
#pragma unroll
                    for (int r = 0; r < 4; r++) {
                        const float val = acc[it][jt][r];
                        const size_t o = ((size_t)(b*Hc + hh)*Tc + t0 + r)*128 + d;
                        bf16_t vh = (bf16_t)val;
                        O[o]      = vh;
                        O[o + 64] = (bf16_t)(val - (float)vh);
                    }
                } else if (sel <= 3) {
                    // transposed split-D: [bh][d][t hi | t lo]
                    const int d = (sel == 3 ? 64 : 0) + (col & 63);
                    bf16x4 h4, l4;
#pragma unroll
                    for (int r = 0; r < 4; r++) {
                        const float val = acc[it][jt][r];
                        h4[r] = (bf16_t)val;
                        l4[r] = (bf16_t)(val - (float)h4[r]);
                    }
                    const size_t o = (size_t)(b*Hc + hh)*TDS + (size_t)d*2048 + t0;
                    *(bf16x4*)&Od[o]        = h4;
                    *(bf16x4*)&Od[o + 1024] = l4;
                } else {
#pragma unroll
                    for (int r = 0; r < 4; r++)
                        Ov[((size_t)(b*Hc + hh)*Tc + t0 + r)*64 + (col & 63)]
                            = acc[it][jt][r];
                }
            } else {
#pragma unroll
                for (int r = 0; r < 4; r++)
                    Opart[(size_t)(mb + r) * DMc + col] = acc[it][jt][r];
            }
        }
    }
}

// ---------------------------------------------------------------------------
// Sum 2 K-slice partials -> out
// ---------------------------------------------------------------------------
__global__ __launch_bounds__(256)
void reduce2_k(const float* __restrict__ p0, const float* __restrict__ p1,
               float* __restrict__ out)
{
    size_t i = ((size_t)blockIdx.x * 256 + threadIdx.x) * 4;
    float4 a = *(const float4*)&p0[i];
    float4 b = *(const float4*)&p1[i];
    *(float4*)&out[i] = make_float4(a.x+b.x, a.y+b.y, a.z+b.z, a.w+b.w);
}

// ---------------------------------------------------------------------------
// Fused propagation step (r5 structure — measured best across r5..r10:
// 256 threads, grid (64,8), 2 blocks/CU, single-buffered LDS, 2 barriers,
// T14 reg-prefetch, shfl P-transform).  Per chunk: {barrier; reg->LDS;
// barrier; prefetch ch+1 into regs; compute}.
// ---------------------------------------------------------------------------
template<int FINAL>
__global__ __launch_bounds__(256)
void prop_k(const bf16_t* __restrict__ Qg, const bf16_t* __restrict__ Kg,
            const bf16_t* __restrict__ DTin, bf16_t* __restrict__ DTout,
            float* __restrict__ Dc, const float* __restrict__ llam)
{
    __shared__ bf16_t Ks[32*KLSTR];    // 8.7 KB: [s][dk hi 64 | dk lo 64 | pad]
    __shared__ bf16_t Ds[128*DLSTR];   // 18.4 KB: [d][s hi 32 | s lo 32 | pad]

    const int tid = threadIdx.x;
    const int wv  = tid >> 6;
    const int ln  = tid & 63;
    const int l15 = ln & 15;
    const int qd  = ln >> 4;
    const int bh  = blockIdx.x;
    const int Tw  = blockIdx.y * 128 + wv * 32;   // this wave's 32 t's

    const bf16_t* Qh  = Qg   + (size_t)bh * (Tc*128);
    const bf16_t* Kh  = Kg   + (size_t)bh * (Tc*128);
    const bf16_t* DTh = DTin + (size_t)bh * TDS;

    // Q B-fragments (lane n=t=l15, k=dk=qd*8+j), loop-invariant
    bf16x8 qfh[2][2], qfl[2][2];     // [tj][ks]
#pragma unroll
    for (int tj = 0; tj < 2; tj++) {
        const bf16_t* qp = &Qh[(size_t)(Tw + tj*16 + l15) * 128];
#pragma unroll
        for (int ks = 0; ks < 2; ks++) {
            qfh[tj][ks] = *(const bf16x8*)&qp[ks*32 + qd*8];
            qfl[tj][ks] = *(const bf16x8*)&qp[64 + ks*32 + qd*8];
        }
    }

    // T14 staging geometry (loop-invariant per-thread src/dst)
    const int idk0 = tid, idk1 = tid + 256;
    const bf16_t* srcK0 = Kh + (size_t)(idk0 >> 4) * 128 + (idk0 & 15) * 8;
    const bf16_t* srcK1 = Kh + (size_t)(idk1 >> 4) * 128 + (idk1 & 15) * 8;
    bf16_t* dstK0 = &Ks[(idk0 >> 4) * KLSTR + (idk0 & 15) * 8];
    bf16_t* dstK1 = &Ks[(idk1 >> 4) * KLSTR + (idk1 & 15) * 8];
    const bf16_t* srcD[4];
    bf16_t* dstD[4];
#pragma unroll
    for (int i = 0; i < 4; i++) {
        const int id = tid + i * 256;
        const int r = id >> 3, sg = id & 7;
        srcD[i] = DTh + (size_t)r * 2048
                      + (sg < 4 ? sg * 8 : 1024 + (sg - 4) * 8);
        dstD[i] = (sg < 4) ? &Ds[r * DLSTR + sg * 8]
                           : &Ds[r * DLSTR + 32 + (sg - 4) * 8];
    }
    // prologue: chunk 0 into regs
    bf16x8 kr0 = *(const bf16x8*)srcK0;
    bf16x8 kr1 = *(const bf16x8*)srcK1;
    bf16x8 dr[4];
#pragma unroll
    for (int i = 0; i < 4; i++) dr[i] = *(const bf16x8*)srcD[i];

    f32x4 acc[8][2];                 // [d-tile][t-tile]
#pragma unroll
    for (int i = 0; i < 8; i++)
#pragma unroll
        for (int j = 0; j < 2; j++) acc[i][j] = (f32x4)0.f;
    float rs[2] = {0.f, 0.f};

    // shfl source lanes for the P layout transform (verified r6)
    const int srcA = (((qd & 1) * 2)     << 4) | l15;
    const int srcB = (((qd & 1) * 2 + 1) << 4) | l15;
    const bool loQuad = (qd < 2);

#pragma unroll 1
    for (int ch = 0; ch < 32; ch++) {
        __syncthreads();              // prev chunk fully consumed; LDS writable
        *(bf16x8*)dstK0 = kr0;
        *(bf16x8*)dstK1 = kr1;
#pragma unroll
        for (int i = 0; i < 4; i++) *(bf16x8*)dstD[i] = dr[i];
        __syncthreads();              // staged data visible
        if (ch < 31) {                // prefetch next chunk under compute
            kr0 = *(const bf16x8*)(srcK0 + (size_t)(ch + 1) * 4096);
            kr1 = *(const bf16x8*)(srcK1 + (size_t)(ch + 1) * 4096);
#pragma unroll
            for (int i = 0; i < 4; i++)
                dr[i] = *(const bf16x8*)(srcD[i] + (size_t)(ch + 1) * 32);
        }
        // ---- K A-fragments from LDS (lane m=s=si*16+l15, k=dk)
        bf16x8 kfh[2][2], kfl[2][2];   // [si][ks]
#pragma unroll
        for (int si = 0; si < 2; si++) {
            const int row = (si*16 + l15) * KLSTR;
#pragma unroll
            for (int ks = 0; ks < 2; ks++) {
                kfh[si][ks] = ld8(&Ks[row + ks*32 + qd*8]);
                kfl[si][ks] = ld8(&Ks[row + 64 + ks*32 + qd*8]);
            }
        }
        // ---- scores^T: C[m=s][n=t]
        f32x4 pacc[2][2];              // [si][tj]
#pragma unroll
        for (int si = 0; si < 2; si++)
#pragma unroll
            for (int tj = 0; tj < 2; tj++) pacc[si][tj] = (f32x4)0.f;
#pragma unroll
        for (int ks = 0; ks < 2; ks++)
#pragma unroll
            for (int si = 0; si < 2; si++)
#pragma unroll
                for (int tj = 0; tj < 2; tj++) {
                    pacc[si][tj] = __builtin_amdgcn_mfma_f32_16x16x32_bf16(
                        kfh[si][ks], qfh[tj][ks], pacc[si][tj], 0, 0, 0);
                    pacc[si][tj] = __builtin_amdgcn_mfma_f32_16x16x32_bf16(
                        kfl[si][ks], qfh[tj][ks], pacc[si][tj], 0, 0, 0);
                    pacc[si][tj] = __builtin_amdgcn_mfma_f32_16x16x32_bf16(
                        kfh[si][ks], qfl[tj][ks], pacc[si][tj], 0, 0, 0);
                }
        // ---- exp + split + pack (lane holds s = si*16 + qd*4 + r for t=l15)
        unsigned pk01h[2][2], pk23h[2][2], pk01l[2][2], pk23l[2][2]; // [si][tj]
#pragma unroll
        for (int si = 0; si < 2; si++)
#pragma unroll
            for (int tj = 0; tj < 2; tj++) {
                float e0 = __expf(pacc[si][tj][0] * 0.125f);
                float e1 = __expf(pacc[si][tj][1] * 0.125f);
                float e2 = __expf(pacc[si][tj][2] * 0.125f);
                float e3 = __expf(pacc[si][tj][3] * 0.125f);
                rs[tj] += (e0 + e1) + (e2 + e3);
                bf16_t h0=(bf16_t)e0, h1=(bf16_t)e1, h2=(bf16_t)e2, h3=(bf16_t)e3;
                pk01h[si][tj] = pk2(h0, h1);
                pk23h[si][tj] = pk2(h2, h3);
                pk01l[si][tj] = pk2((bf16_t)(e0-(float)h0), (bf16_t)(e1-(float)h1));
                pk23l[si][tj] = pk2((bf16_t)(e2-(float)h2), (bf16_t)(e3-(float)h3));
            }
        // ---- P -> B-operand fragments via shfl (dest: n=t=l15, k=s=qd*8+j)
        bf16x8 pfh[2], pfl[2];
#pragma unroll
        for (int tj = 0; tj < 2; tj++) {
            union { bf16x8 v; unsigned u[4]; } H, L;
            unsigned a0 = __shfl((int)pk01h[0][tj], srcA, 64);
            unsigned a1 = __shfl((int)pk23h[0][tj], srcA, 64);
            unsigned a2 = __shfl((int)pk01h[0][tj], srcB, 64);
            unsigned a3 = __shfl((int)pk23h[0][tj], srcB, 64);
            unsigned b0 = __shfl((int)pk01h[1][tj], srcA, 64);
            unsigned b1 = __shfl((int)pk23h[1][tj], srcA, 64);
            unsigned b2 = __shfl((int)pk01h[1][tj], srcB, 64);
            unsigned b3 = __shfl((int)pk23h[1][tj], srcB, 64);
            H.u[0] = loQuad ? a0 : b0;  H.u[1] = loQuad ? a1 : b1;
            H.u[2] = loQuad ? a2 : b2;  H.u[3] = loQuad ? a3 : b3;
            unsigned c0 = __shfl((int)pk01l[0][tj], srcA, 64);
            unsigned c1 = __shfl((int)pk23l[0][tj], srcA, 64);
            unsigned c2 = __shfl((int)pk01l[0][tj], srcB, 64);
            unsigned c3 = __shfl((int)pk23l[0][tj], srcB, 64);
            unsigned d0_ = __shfl((int)pk01l[1][tj], srcA, 64);
            unsigned d1 = __shfl((int)pk23l[1][tj], srcA, 64);
            unsigned d2 = __shfl((int)pk01l[1][tj], srcB, 64);
            unsigned d3 = __shfl((int)pk23l[1][tj], srcB, 64);
            L.u[0] = loQuad ? c0 : d0_; L.u[1] = loQuad ? c1 : d1;
            L.u[2] = loQuad ? c2 : d2;  L.u[3] = loQuad ? c3 : d3;
            pfh[tj] = H.v; pfl[tj] = L.v;
        }
        // ---- main: acc[d][t] += D x P  (D A-frags from LDS, 2 halves)
#pragma unroll
        for (int half = 0; half < 2; half++) {
            bf16x8 dfh[4], dfl[4];
#pragma unroll
            for (int i = 0; i < 4; i++) {
                const int row = ((half*4 + i)*16 + l15) * DLSTR;
                dfh[i] = ld8(&Ds[row + qd*8]);
                dfl[i] = ld8(&Ds[row + 32 + qd*8]);
            }
#pragma unroll
            for (int i = 0; i < 4; i++)
#pragma unroll
                for (int tj = 0; tj < 2; tj++) {
                    acc[half*4+i][tj] = __builtin_amdgcn_mfma_f32_16x16x32_bf16(
                        dfh[i], pfh[tj], acc[half*4+i][tj], 0, 0, 0);
                    acc[half*4+i][tj] = __builtin_amdgcn_mfma_f32_16x16x32_bf16(
                        dfh[i], pfl[tj], acc[half*4+i][tj], 0, 0, 0);
                    acc[half*4+i][tj] = __builtin_amdgcn_mfma_f32_16x16x32_bf16(
                        dfl[i], pfh[tj], acc[half*4+i][tj], 0, 0, 0);
                }
        }
    }

    // ---- finalize row sums: reduce across quads (lane bits 4,5)
#pragma unroll
    for (int tj = 0; tj < 2; tj++) {
        rs[tj] += __shfl_xor(rs[tj], 16);
        rs[tj] += __shfl_xor(rs[tj], 32);
    }

    const float lam = 1.f / (1.f + __expf(-llam[0]));
    const float oml = 1.f - lam;
    bf16_t* DToutg = (FINAL ? (bf16_t*)nullptr : DTout + (size_t)bh * TDS);

#pragma unroll
    for (int tj = 0; tj < 2; tj++) {
        const int t = Tw + tj*16 + l15;          // C col (global t)
        const float s = lam / rs[tj];
#pragma unroll
        for (int it = 0; it < 8; it++) {
            const int d0 = it*16 + qd*4;         // C rows d0..d0+3
            float v[4];
#pragma unroll
            for (int r = 0; r < 4; r++) {
                const size_t ro = (size_t)(d0 + r)*2048 + t;
                float res = (float)DTh[ro] + (float)DTh[ro + 1024];
                v[r] = oml*res + s*acc[it][tj][r];
            }
            if (FINAL) {
                *(float4*)&Dc[((size_t)bh*Tc + t)*128 + d0] =
                    make_float4(v[0], v[1], v[2], v[3]);
            } else {
#pragma unroll
                for (int r = 0; r < 4; r++) {
                    const size_t ro = (size_t)(d0 + r)*2048 + t;
                    bf16_t h = (bf16_t)v[r];
                    DToutg[ro]        = h;
                    DToutg[ro + 1024] = (bf16_t)(v[r] - (float)h);
                }
            }
        }
    }
}

// ---------------------------------------------------------------------------
// mean over T, two-stage for full-GPU occupancy
// ---------------------------------------------------------------------------
__global__ __launch_bounds__(256)
void mean1_k(const float* __restrict__ D,
             float* __restrict__ M1re, float* __restrict__ M1im)
{
    __shared__ float sre[4][64], sim[4][64];
    const int bh = blockIdx.x, y = blockIdx.y;
    const int d = threadIdx.x & 63, q = threadIdx.x >> 6;
    const float* p = D + (size_t)bh * TD2;
    float ar = 0.f, ai = 0.f;
    const int t0 = y*128 + q*32;
    for (int t = t0; t < t0 + 32; t++) {
        ar += p[t*128 + d]; ai += p[t*128 + 64 + d];
    }
    sre[q][d] = ar; sim[q][d] = ai;
    __syncthreads();
    if (threadIdx.x < 64) {
        M1re[(bh*8 + y)*64 + d] = sre[0][d]+sre[1][d]+sre[2][d]+sre[3][d];
        M1im[(bh*8 + y)*64 + d] = sim[0][d]+sim[1][d]+sim[2][d]+sim[3][d];
    }
}

__global__ __launch_bounds__(64)
void mean2_k(const float* __restrict__ M1re, const float* __restrict__ M1im,
             float* __restrict__ Mre, float* __restrict__ Mim)
{
    const int bh = blockIdx.x, d = threadIdx.x;
    float r = 0.f, im = 0.f;
    for (int y = 0; y < 8; y++) {
        r  += M1re[(bh*8 + y)*64 + d];
        im += M1im[(bh*8 + y)*64 + d];
    }
    Mre[bh*64 + d] = r  * (1.f/1024.f);
    Mim[bh*64 + d] = im * (1.f/1024.f);
}

// ---------------------------------------------------------------------------
// gate softmax over T, two-stage (partial denominators, then normalize+emit)
// ---------------------------------------------------------------------------
__global__ __launch_bounds__(256)
void gate1_k(const float* __restrict__ D,
             const float* __restrict__ Mre, const float* __restrict__ Mim,
             float* __restrict__ Gp)
{
    __shared__ float part[4][64];
    const int bh = blockIdx.x, y = blockIdx.y;
    const int d = threadIdx.x & 63, q = threadIdx.x >> 6;
    const float* p = D + (size_t)bh * TD2;
    const float mre = Mre[bh*64 + d], mim = Mim[bh*64 + d];
    const float mabs = sqrtf(mre*mre + mim*mim);

    float ps = 0.f;
    const int t0 = y*128 + q*32;
    for (int t = t0; t < t0 + 32; t++) {
        float dr = p[t*128 + d], dv = p[t*128 + 64 + d];
        float c = (dr*mre + dv*mim) / (sqrtf(dr*dr + dv*dv)*mabs + 1e-8f);
        ps += __expf(c);
    }
    part[q][d] = ps;
    __syncthreads();
    if (threadIdx.x < 64)
        Gp[(bh*8 + y)*64 + d] = part[0][d]+part[1][d]+part[2][d]+part[3][d];
}

__global__ __launch_bounds__(256)
void gate2_k(const float* __restrict__ D,
             const float* __restrict__ Mre, const float* __restrict__ Mim,
             const float* __restrict__ V, const float* __restrict__ Gp,
             float* __restrict__ gate_out,
             bf16_t* __restrict__ gVh, bf16_t* __restrict__ gVl)
{
    __shared__ float dinv[64];
    const int bh = blockIdx.x, y = blockIdx.y;
    const int d = threadIdx.x & 63, q = threadIdx.x >> 6;
    if (threadIdx.x < 64) {
        float s = 0.f;
        for (int yy = 0; yy < 8; yy++) s += Gp[(bh*8 + yy)*64 + d];
        dinv[d] = 1.f / s;
    }
    __syncthreads();

    const float* p = D + (size_t)bh * TD2;
    const float mre = Mre[bh*64 + d], mim = Mim[bh*64 + d];
    const float mabs = sqrtf(mre*mre + mim*mim);
    const float di_ = dinv[d];
    const int b = bh >> 4, hh = bh & 15;
    const float* pv = V + (size_t)bh * TD;
    const int t0 = y*128 + q*32;
    for (int t = t0; t < t0 + 32; t++) {
        float dr = p[t*128 + d], dv = p[t*128 + 64 + d];
        float c = (dr*mre + dv*mim) / (sqrtf(dr*dr + dv*dv)*mabs + 1e-8f);
        float g = __expf(c) * di_;
        gate_out[(size_t)bh*TD + t*64 + d] = g;
        float gv = g * pv[t*64 + d];
        size_t o = ((size_t)b*Tc + t)*DMc + hh*64 + d;
        bf16_t gh = (bf16_t)gv;
        gVh[o] = gh;
        gVl[o] = (bf16_t)(gv - (float)gh);
    }
}

// ---------------------------------------------------------------------------
extern "C" void kernel_launch(void* const* d_in, const int* in_sizes, int n_in,
                              void* d_out, int out_size, void* d_ws, size_t ws_size,
                              hipStream_t stream)
{
    const float* x    = (const float*)d_in[0];
    const float* W_Q  = (const float*)d_in[1];
    const float* W_K  = (const float*)d_in[2];
    const float* W_re = (const float*)d_in[3];
    const float* W_im = (const float*)d_in[4];
    const float* W_V  = (const float*)d_in[5];
    const float* W_O  = (const float*)d_in[6];
    const float* llam = (const float*)d_in[7];

    float* out      = (float*)d_out;
    float* gate_out = out + (size_t)Mc * DMc;

    float* ws = (float*)d_ws;
    const size_t M1 = 1024*1024;
    float*  Dc  = ws;                          // 32 MB — aliases DT1
    bf16_t* DT1 = (bf16_t*)ws;                 // 16M bf16
    bf16_t* DT0 = (bf16_t*)(ws + 8*M1);        // 16M bf16 (32 MB)
    float*  V   = ws + 16*M1;                  // 16 MB
    bf16_t* Qs  = (bf16_t*)(ws + 20*M1);       // 16 MB
    bf16_t* Ksb = (bf16_t*)(ws + 24*M1);       // 16 MB
    float*  Mre = ws + 28*M1;
    float*  Mim = Mre + 4096;
    bf16_t* xh  = (bf16_t*)(ws + 28*M1 + 8192);// 8 MB
    bf16_t* xl  = xh + 4*M1;                   // 8 MB
    bf16_t* WT  = xl + 4*M1;                   // 24 MB
    bf16_t* gVh = xh;                          // alias: x dead after mgemm<0>
    bf16_t* gVl = xl;
    // scratch for mean/gate two-stage: Ksb region (dead after prop_k)
    float* Gp   = ws + 24*M1;                  // 64*8*64 f32
    float* M1re = Gp + 32768;
    float* M1im = M1re + 32768;
    // K-slice partials for mgemm<1> (K-split x2): DT0 region, dead after prop.
    float* P0 = ws + 8*M1;
    float* P1 = ws + 12*M1;

    convx_k<<<4096, 256, 0, stream>>>(x, xh, xl);
    convw_k<<<dim3(32, 32, 6), 256, 0, stream>>>(
        W_Q, W_K, W_re, W_im, W_V, W_O, WT);

    // projections: Q,K -> split slabs; Dre/Dim -> DT0 (transposed split); V f32
    mgemm_k<0><<<dim3(32, 40), 256, 0, stream>>>(
        xh, xl, WT, Qs, Ksb, DT0, V, nullptr);

    prop_k<0><<<dim3(64, 8), 256, 0, stream>>>(Qs, Ksb, DT0, DT1, nullptr, llam);
    prop_k<0><<<dim3(64, 8), 256, 0, stream>>>(Qs, Ksb, DT1, DT0, nullptr, llam);
    prop_k<1><<<dim3(64, 8), 256, 0, stream>>>(Qs, Ksb, DT0, nullptr, Dc, llam);

    mean1_k<<<dim3(64, 8), 256, 0, stream>>>(Dc, M1re, M1im);
    mean2_k<<<64, 64, 0, stream>>>(M1re, M1im, Mre, Mim);
    gate1_k<<<dim3(64, 8), 256, 0, stream>>>(Dc, Mre, Mim, Gp);
    gate2_k<<<dim3(64, 8), 256, 0, stream>>>(Dc, Mre, Mim, V, Gp,
                                             gate_out, gVh, gVl);

    // out = gateV @ W_O, K-split x2 into partials, then reduce
    mgemm_k<1><<<dim3(32, 8, 2), 256, 0, stream>>>(
        gVh, gVl, WT, nullptr, nullptr, nullptr, nullptr, P0);
    reduce2_k<<<4096, 256, 0, stream>>>(P0, P1, out);
}

// Round 12
// 575.382 us; speedup vs baseline: 1.1537x; 1.0536x over previous
//
#include <hip/hip_runtime.h>
#include <math.h>

// Problem constants
#define Bc 4
#define Tc 1024
#define DMc 1024
#define Hc 16
#define DKc 64
#define BHc 64          // B*H
#define Mc 4096         // B*T
#define TD (Tc*DKc)     // 65536 el per (b,h) slab, stride-64 layout
#define TD2 (Tc*128)    // combined re|im slab, stride-128 layout
#define TDS (128*2048)  // split-D slab: [d(128)][s hi 1024 | s lo 1024] bf16

typedef __bf16 bf16_t;
typedef bf16_t bf16x4 __attribute__((ext_vector_type(4)));
typedef bf16_t bf16x8 __attribute__((ext_vector_type(8)));
typedef float  f32x4  __attribute__((ext_vector_type(4)));

#define KLSTR 136  // prop: K tile row stride (bf16): [hi 64|lo 64|pad 8] — 272B, 16B-aligned rows
#define DLSTR 72   // prop: D tile row stride (bf16): [hi 32|lo 32|pad 8] — 144B, 16B-aligned rows

__device__ __forceinline__ bf16x8 ld8(const bf16_t* p) {
    return *(const bf16x8*)p;   // ds_read_b128 (all call sites 16B-aligned)
}
__device__ __forceinline__ void packsplit4(bf16_t* dh, bf16_t* dl, float4 v) {
    bf16x4 h, l;
    h[0]=(bf16_t)v.x; l[0]=(bf16_t)(v.x-(float)h[0]);
    h[1]=(bf16_t)v.y; l[1]=(bf16_t)(v.y-(float)h[1]);
    h[2]=(bf16_t)v.z; l[2]=(bf16_t)(v.z-(float)h[2]);
    h[3]=(bf16_t)v.w; l[3]=(bf16_t)(v.w-(float)h[3]);
    *(bf16x4*)dh = h; *(bf16x4*)dl = l;
}
__device__ __forceinline__ unsigned pk2(bf16_t a, bf16_t b) {
    unsigned short ua = __builtin_bit_cast(unsigned short, a);
    unsigned short ub = __builtin_bit_cast(unsigned short, b);
    return (unsigned)ua | ((unsigned)ub << 16);
}
// async global->LDS, 16B per lane; lds dest must be wave-uniform base.
__device__ __forceinline__ void gload16(const bf16_t* g, bf16_t* l) {
    __builtin_amdgcn_global_load_lds(
        (__attribute__((address_space(1))) void*)(bf16_t*)g,
        (__attribute__((address_space(3))) void*)l, 16, 0, 0);
}

// ---------------------------------------------------------------------------
// Convert x (4096x1024 f32) -> xh, xl bf16
// ---------------------------------------------------------------------------
__global__ __launch_bounds__(256)
void convx_k(const float* __restrict__ x,
             bf16_t* __restrict__ xh, bf16_t* __restrict__ xl)
{
    size_t i = ((size_t)blockIdx.x * 256 + threadIdx.x) * 4;
    float4 v = *(const float4*)&x[i];
    packsplit4(&xh[i], &xl[i], v);
}

// ---------------------------------------------------------------------------
// Convert + transpose each W (1024x1024 f32 [k][n]) -> WT hi/lo bf16 [n][k].
// ---------------------------------------------------------------------------
__global__ __launch_bounds__(256)
void convw_k(const float* __restrict__ W0, const float* __restrict__ W1,
             const float* __restrict__ W2, const float* __restrict__ W3,
             const float* __restrict__ W4, const float* __restrict__ W5,
             bf16_t* __restrict__ WT)
{
    __shared__ float tile[32][33];
    const float* Ws[6] = {W0, W1, W2, W3, W4, W5};
    const int wi = blockIdx.z;
    const float* W = Ws[wi];
    bf16_t* WTh = WT + (size_t)wi * 2097152;
    bf16_t* WTl = WTh + 1048576;

    const int tx = threadIdx.x & 31, ty = threadIdx.x >> 5;
    const int k0 = blockIdx.x * 32, n0 = blockIdx.y * 32;
#pragma unroll
    for (int i = 0; i < 4; i++)
        tile[ty + 8*i][tx] = W[(size_t)(k0 + ty + 8*i) * DMc + n0 + tx];
    __syncthreads();
    const int kg = threadIdx.x & 7, n = threadIdx.x >> 3;
    float4 v = make_float4(tile[kg*4+0][n], tile[kg*4+1][n],
                           tile[kg*4+2][n], tile[kg*4+3][n]);
    const size_t o = (size_t)(n0 + n) * DMc + k0 + kg*4;
    packsplit4(&WTh[o], &WTl[o], v);
}

// ---------------------------------------------------------------------------
// Split-bf16 MFMA GEMM (3 products, f32 accum). A [m][k] hi/lo; B = WT [n][k].
// Staging via global_load_lds width=16 into linear [128][32] LDS tiles.
// MODE 0 (grid 32x24): by>>3 selects pair {Q,K}/{Dre,Dim}/{V alone}; one
//   block computes BOTH outputs of the pair from a single staged A-tile
//   (halves A staging + A-fragment reads; MFMA sequences per output are
//   unchanged -> bitwise-identical results).
// MODE 1: single-B (W_O), K-split x2 (blockIdx.z selects K=512 slice),
//   f32 partials at Of + z*4M floats; reduced by reduce2_k.
// ---------------------------------------------------------------------------
template<int MODE>
__global__ __launch_bounds__(256, 2)
void mgemm_k(const bf16_t* __restrict__ Ah, const bf16_t* __restrict__ Al,
             const bf16_t* __restrict__ WT,
             bf16_t* __restrict__ Oq, bf16_t* __restrict__ Ok,
             bf16_t* __restrict__ Od, float* __restrict__ Ov,
             float* __restrict__ Of)
{
    __shared__ bf16_t S[6][128*32];   // 48 KB: Ah, Al, B0h, B0l, B1h, B1l

    const int tid = threadIdx.x;
    const int wv  = tid >> 6;
    const int ln  = tid & 63;
    const int l15 = ln & 15;
    const int qd  = ln >> 4;
    const int m0  = blockIdx.x * 128;
    const int by  = blockIdx.y;

    int n0, sel0, kt0, kt1;
    bool two;
    float* Opart;
    if (MODE == 0) {
        const int pi = by >> 3;
        sel0 = pi * 2;            // 0,2 -> pairs; 4 -> V alone
        two  = (pi < 2);
        n0 = (by & 7) * 128;
        kt0 = 0; kt1 = DMc;
        Opart = nullptr;
    } else {
        sel0 = 5;
        two  = false;
        n0 = by * 128;
        kt0 = blockIdx.z * 512; kt1 = kt0 + 512;
        Opart = Of + (size_t)blockIdx.z * ((size_t)Mc * DMc);
    }
    const bf16_t* B0h = WT + (size_t)sel0 * 2097152;
    const bf16_t* B0l = B0h + 1048576;
    const bf16_t* B1h = B0h + 2097152;   // only staged when two
    const bf16_t* B1l = B1h + 1048576;

    // staging geometry: per instr i (0..7), lane ln covers LDS elements
    // [i*512 + ln*8, +8)  ->  row = i*16 + (ln>>2), col = (ln&3)*8
    const int srow = ln >> 2;
    const int scol = (ln & 3) * 8;
    const bf16_t* gAh = Ah  + (size_t)(m0 + srow) * DMc + scol + kt0;
    const bf16_t* gAl = Al  + (size_t)(m0 + srow) * DMc + scol + kt0;
    const bf16_t* gB0h = B0h + (size_t)(n0 + srow) * DMc + scol + kt0;
    const bf16_t* gB0l = B0l + (size_t)(n0 + srow) * DMc + scol + kt0;
    const bf16_t* gB1h = B1h + (size_t)(n0 + srow) * DMc + scol + kt0;
    const bf16_t* gB1l = B1l + (size_t)(n0 + srow) * DMc + scol + kt0;

    f32x4 acc[2][4][4];
#pragma unroll
    for (int p = 0; p < 2; p++)
#pragma unroll
    for (int i = 0; i < 4; i++)
#pragma unroll
        for (int j = 0; j < 4; j++) acc[p][i][j] = (f32x4)0.f;

#pragma unroll 1
    for (int kt = kt0; kt < kt1; kt += 32) {
        __syncthreads();   // previous tile fully consumed
        if (two) {
            // 6-tensor staging: 12 gloads per wave
            if (wv == 0) {
#pragma unroll
                for (int i = 0; i < 8; i++)
                    gload16(gAh + (size_t)i * 16 * DMc, &S[0][i * 512]);
#pragma unroll
                for (int i = 0; i < 4; i++)
                    gload16(gAl + (size_t)i * 16 * DMc, &S[1][i * 512]);
            } else if (wv == 1) {
#pragma unroll
                for (int i = 4; i < 8; i++)
                    gload16(gAl + (size_t)i * 16 * DMc, &S[1][i * 512]);
#pragma unroll
                for (int i = 0; i < 8; i++)
                    gload16(gB0h + (size_t)i * 16 * DMc, &S[2][i * 512]);
            } else if (wv == 2) {
#pragma unroll
                for (int i = 0; i < 8; i++)
                    gload16(gB0l + (size_t)i * 16 * DMc, &S[3][i * 512]);
#pragma unroll
                for (int i = 0; i < 4; i++)
                    gload16(gB1h + (size_t)i * 16 * DMc, &S[4][i * 512]);
            } else {
#pragma unroll
                for (int i = 4; i < 8; i++)
                    gload16(gB1h + (size_t)i * 16 * DMc, &S[4][i * 512]);
#pragma unroll
                for (int i = 0; i < 8; i++)
                    gload16(gB1l + (size_t)i * 16 * DMc, &S[5][i * 512]);
            }
        } else {
            // 4-tensor staging: wave wv handles tensor wv
            const bf16_t* sb = (wv == 0) ? gAh : (wv == 1) ? gAl
                              : (wv == 2) ? gB0h : gB0l;
            bf16_t* ld = &S[wv][0];
#pragma unroll
            for (int i = 0; i < 8; i++)
                gload16(sb + (size_t)i * 16 * DMc, ld + i * 512);
        }
        gAh += 32; gAl += 32; gB0h += 32; gB0l += 32; gB1h += 32; gB1l += 32;
        __syncthreads();   // vmcnt drained before barrier -> tile visible

        bf16x8 fah[4], fal[4];
#pragma unroll
        for (int it = 0; it < 4; it++) {
            const int row = ((wv>>1)*64 + it*16 + l15) * 32 + qd*8;
            fah[it] = *(const bf16x8*)&S[0][row];
            fal[it] = *(const bf16x8*)&S[1][row];
        }
        // p = 0 (B-fragments loaded per-p to bound register pressure)
        {
            bf16x8 fbh[4], fbl[4];
#pragma unroll
            for (int jt = 0; jt < 4; jt++) {
                const int row = ((wv&1)*64 + jt*16 + l15) * 32 + qd*8;
                fbh[jt] = *(const bf16x8*)&S[2][row];
                fbl[jt] = *(const bf16x8*)&S[3][row];
            }
#pragma unroll
            for (int it = 0; it < 4; it++)
#pragma unroll
                for (int jt = 0; jt < 4; jt++) {
                    acc[0][it][jt] = __builtin_amdgcn_mfma_f32_16x16x32_bf16(
                        fah[it], fbh[jt], acc[0][it][jt], 0, 0, 0);
                    acc[0][it][jt] = __builtin_amdgcn_mfma_f32_16x16x32_bf16(
                        fah[it], fbl[jt], acc[0][it][jt], 0, 0, 0);
                    acc[0][it][jt] = __builtin_amdgcn_mfma_f32_16x16x32_bf16(
                        fal[it], fbh[jt], acc[0][it][jt], 0, 0, 0);
                }
        }
        if (two) {   // p = 1
            bf16x8 fbh[4], fbl[4];
#pragma unroll
            for (int jt = 0; jt < 4; jt++) {
                const int row = ((wv&1)*64 + jt*16 + l15) * 32 + qd*8;
                fbh[jt] = *(const bf16x8*)&S[4][row];
                fbl[jt] = *(const bf16x8*)&S[5][row];
            }
#pragma unroll
            for (int it = 0; it < 4; it++)
#pragma unroll
                for (int jt = 0; jt < 4; jt++) {
                    acc[1][it][jt] = __builtin_amdgcn_mfma_f32_16x16x32_bf16(
                        fah[it], fbh[jt], acc[1][it][jt], 0, 0, 0);
                    acc[1][it][jt] = __builtin_amdgcn_mfma_f32_16x16x32_bf16(
                        fah[it], fbl[jt], acc[1][it][jt], 0, 0, 0);
                    acc[1][it][jt] = __builtin_amdgcn_mfma_f32_16x16x32_bf16(
                        fal[it], fbh[jt], acc[1][it][jt], 0, 0, 0);
                }
        }
    }

#pragma unroll
    for (int p = 0; p < 2; p++) {
        if (p == 1 && !two) continue;
        const int sel = (MODE == 0) ? sel0 + p : 5;
#pragma unroll
        for (int it = 0; it < 4; it++) {
            const int mb = m0 + (wv>>1)*64 + it*16 + qd*4;
#pragma unroll
            for (int jt = 0; jt < 4; jt++) {
                const int col = n0 + (wv&1)*64 + jt*16 + l15;
                if (MODE == 0) {
                    const int hh = col >> 6;
                    const int b  = mb >> 10, t0 = mb & 1023;
                    if (sel <= 1) {
                        bf16_t* O = sel ? Ok : Oq;
                        const int d = col & 63;
#pragma unroll
                        for (int r = 0; r < 4; r++) {
                            const float val = acc[p][it][jt][r];
                            const size_t o = ((size_t)(b*Hc + hh)*Tc + t0 + r)*128 + d;
                            bf16_t vh = (bf16_t)val;
                            O[o]      = vh;
                            O[o + 64] = (bf16_t)(val - (float)vh);
                        }
                    } else if (sel <= 3) {
                        // transposed split-D: [bh][d][t hi | t lo]
                        const int d = (sel == 3 ? 64 : 0) + (col & 63);
                        bf16x4 h4, l4;
#pragma unroll
                        for (int r = 0; r < 4; r++) {
                            const float val = acc[p][it][jt][r];
                            h4[r] = (bf16_t)val;
                            l4[r] = (bf16_t)(val - (float)h4[r]);
                        }
                        const size_t o = (size_t)(b*Hc + hh)*TDS + (size_t)d*2048 + t0;
                        *(bf16x4*)&Od[o]        = h4;
                        *(bf16x4*)&Od[o + 1024] = l4;
                    } else {
#pragma unroll
                        for (int r = 0; r < 4; r++)
                            Ov[((size_t)(b*Hc + hh)*Tc + t0 + r)*64 + (col & 63)]
                                = acc[p][it][jt][r];
                    }
                } else {
#pragma unroll
                    for (int r = 0; r < 4; r++)
                        Opart[(size_t)(mb + r) * DMc + col] = acc[p][it][jt][r];
                }
            }
        }
    }
}

// ---------------------------------------------------------------------------
// Sum 2 K-slice partials -> out
// ---------------------------------------------------------------------------
__global__ __launch_bounds__(256)
void reduce2_k(const float* __restrict__ p0, const float* __restrict__ p1,
               float* __restrict__ out)
{
    size_t i = ((size_t)blockIdx.x * 256 + threadIdx.x) * 4;
    float4 a = *(const float4*)&p0[i];
    float4 b = *(const float4*)&p1[i];
    *(float4*)&out[i] = make_float4(a.x+b.x, a.y+b.y, a.z+b.z, a.w+b.w);
}

// ---------------------------------------------------------------------------
// Fused propagation step (r5 structure — measured best across r5..r10:
// 256 threads, grid (64,8), 2 blocks/CU, single-buffered LDS, 2 barriers,
// T14 reg-prefetch, shfl P-transform).  Per chunk: {barrier; reg->LDS;
// barrier; prefetch ch+1 into regs; compute}.
// ---------------------------------------------------------------------------
template<int FINAL>
__global__ __launch_bounds__(256)
void prop_k(const bf16_t* __restrict__ Qg, const bf16_t* __restrict__ Kg,
            const bf16_t* __restrict__ DTin, bf16_t* __restrict__ DTout,
            float* __restrict__ Dc, const float* __restrict__ llam)
{
    __shared__ bf16_t Ks[32*KLSTR];    // 8.7 KB: [s][dk hi 64 | dk lo 64 | pad]
    __shared__ bf16_t Ds[128*DLSTR];   // 18.4 KB: [d][s hi 32 | s lo 32 | pad]

    const int tid = threadIdx.x;
    const int wv  = tid >> 6;
    const int ln  = tid & 63;
    const int l15 = ln & 15;
    const int qd  = ln >> 4;
    const int bh  = blockIdx.x;
    const int Tw  = blockIdx.y * 128 + wv * 32;   // this wave's 32 t's

    const bf16_t* Qh  = Qg   + (size_t)bh * (Tc*128);
    const bf16_t* Kh  = Kg   + (size_t)bh * (Tc*128);
    const bf16_t* DTh = DTin + (size_t)bh * TDS;

    // Q B-fragments (lane n=t=l15, k=dk=qd*8+j), loop-invariant
    bf16x8 qfh[2][2], qfl[2][2];     // [tj][ks]
#pragma unroll
    for (int tj = 0; tj < 2; tj++) {
        const bf16_t* qp = &Qh[(size_t)(Tw + tj*16 + l15) * 128];
#pragma unroll
        for (int ks = 0; ks < 2; ks++) {
            qfh[tj][ks] = *(const bf16x8*)&qp[ks*32 + qd*8];
            qfl[tj][ks] = *(const bf16x8*)&qp[64 + ks*32 + qd*8];
        }
    }

    // T14 staging geometry (loop-invariant per-thread src/dst)
    const int idk0 = tid, idk1 = tid + 256;
    const bf16_t* srcK0 = Kh + (size_t)(idk0 >> 4) * 128 + (idk0 & 15) * 8;
    const bf16_t* srcK1 = Kh + (size_t)(idk1 >> 4) * 128 + (idk1 & 15) * 8;
    bf16_t* dstK0 = &Ks[(idk0 >> 4) * KLSTR + (idk0 & 15) * 8];
    bf16_t* dstK1 = &Ks[(idk1 >> 4) * KLSTR + (idk1 & 15) * 8];
    const bf16_t* srcD[4];
    bf16_t* dstD[4];
#pragma unroll
    for (int i = 0; i < 4; i++) {
        const int id = tid + i * 256;
        const int r = id >> 3, sg = id & 7;
        srcD[i] = DTh + (size_t)r * 2048
                      + (sg < 4 ? sg * 8 : 1024 + (sg - 4) * 8);
        dstD[i] = (sg < 4) ? &Ds[r * DLSTR + sg * 8]
                           : &Ds[r * DLSTR + 32 + (sg - 4) * 8];
    }
    // prologue: chunk 0 into regs
    bf16x8 kr0 = *(const bf16x8*)srcK0;
    bf16x8 kr1 = *(const bf16x8*)srcK1;
    bf16x8 dr[4];
#pragma unroll
    for (int i = 0; i < 4; i++) dr[i] = *(const bf16x8*)srcD[i];

    f32x4 acc[8][2];                 // [d-tile][t-tile]
#pragma unroll
    for (int i = 0; i < 8; i++)
#pragma unroll
        for (int j = 0; j < 2; j++) acc[i][j] = (f32x4)0.f;
    float rs[2] = {0.f, 0.f};

    // shfl source lanes for the P layout transform (verified r6)
    const int srcA = (((qd & 1) * 2)     << 4) | l15;
    const int srcB = (((qd & 1) * 2 + 1) << 4) | l15;
    const bool loQuad = (qd < 2);

#pragma unroll 1
    for (int ch = 0; ch < 32; ch++) {
        __syncthreads();              // prev chunk fully consumed; LDS writable
        *(bf16x8*)dstK0 = kr0;
        *(bf16x8*)dstK1 = kr1;
#pragma unroll
        for (int i = 0; i < 4; i++) *(bf16x8*)dstD[i] = dr[i];
        __syncthreads();              // staged data visible
        if (ch < 31) {                // prefetch next chunk under compute
            kr0 = *(const bf16x8*)(srcK0 + (size_t)(ch + 1) * 4096);
            kr1 = *(const bf16x8*)(srcK1 + (size_t)(ch + 1) * 4096);
#pragma unroll
            for (int i = 0; i < 4; i++)
                dr[i] = *(const bf16x8*)(srcD[i] + (size_t)(ch + 1) * 32);
        }
        // ---- K A-fragments from LDS (lane m=s=si*16+l15, k=dk)
        bf16x8 kfh[2][2], kfl[2][2];   // [si][ks]
#pragma unroll
        for (int si = 0; si < 2; si++) {
            const int row = (si*16 + l15) * KLSTR;
#pragma unroll
            for (int ks = 0; ks < 2; ks++) {
                kfh[si][ks] = ld8(&Ks[row + ks*32 + qd*8]);
                kfl[si][ks] = ld8(&Ks[row + 64 + ks*32 + qd*8]);
            }
        }
        // ---- scores^T: C[m=s][n=t]
        f32x4 pacc[2][2];              // [si][tj]
#pragma unroll
        for (int si = 0; si < 2; si++)
#pragma unroll
            for (int tj = 0; tj < 2; tj++) pacc[si][tj] = (f32x4)0.f;
#pragma unroll
        for (int ks = 0; ks < 2; ks++)
#pragma unroll
            for (int si = 0; si < 2; si++)
#pragma unroll
                for (int tj = 0; tj < 2; tj++) {
                    pacc[si][tj] = __builtin_amdgcn_mfma_f32_16x16x32_bf16(
                        kfh[si][ks], qfh[tj][ks], pacc[si][tj], 0, 0, 0);
                    pacc[si][tj] = __builtin_amdgcn_mfma_f32_16x16x32_bf16(
                        kfl[si][ks], qfh[tj][ks], pacc[si][tj], 0, 0, 0);
                    pacc[si][tj] = __builtin_amdgcn_mfma_f32_16x16x32_bf16(
                        kfh[si][ks], qfl[tj][ks], pacc[si][tj], 0, 0, 0);
                }
        // ---- exp + split + pack (lane holds s = si*16 + qd*4 + r for t=l15)
        unsigned pk01h[2][2], pk23h[2][2], pk01l[2][2], pk23l[2][2]; // [si][tj]
#pragma unroll
        for (int si = 0; si < 2; si++)
#pragma unroll
            for (int tj = 0; tj < 2; tj++) {
                float e0 = __expf(pacc[si][tj][0] * 0.125f);
                float e1 = __expf(pacc[si][tj][1] * 0.125f);
                float e2 = __expf(pacc[si][tj][2] * 0.125f);
                float e3 = __expf(pacc[si][tj][3] * 0.125f);
                rs[tj] += (e0 + e1) + (e2 + e3);
                bf16_t h0=(bf16_t)e0, h1=(bf16_t)e1, h2=(bf16_t)e2, h3=(bf16_t)e3;
                pk01h[si][tj] = pk2(h0, h1);
                pk23h[si][tj] = pk2(h2, h3);
                pk01l[si][tj] = pk2((bf16_t)(e0-(float)h0), (bf16_t)(e1-(float)h1));
                pk23l[si][tj] = pk2((bf16_t)(e2-(float)h2), (bf16_t)(e3-(float)h3));
            }
        // ---- P -> B-operand fragments via shfl (dest: n=t=l15, k=s=qd*8+j)
        bf16x8 pfh[2], pfl[2];
#pragma unroll
        for (int tj = 0; tj < 2; tj++) {
            union { bf16x8 v; unsigned u[4]; } H, L;
            unsigned a0 = __shfl((int)pk01h[0][tj], srcA, 64);
            unsigned a1 = __shfl((int)pk23h[0][tj], srcA, 64);
            unsigned a2 = __shfl((int)pk01h[0][tj], srcB, 64);
            unsigned a3 = __shfl((int)pk23h[0][tj], srcB, 64);
            unsigned b0 = __shfl((int)pk01h[1][tj], srcA, 64);
            unsigned b1 = __shfl((int)pk23h[1][tj], srcA, 64);
            unsigned b2 = __shfl((int)pk01h[1][tj], srcB, 64);
            unsigned b3 = __shfl((int)pk23h[1][tj], srcB, 64);
            H.u[0] = loQuad ? a0 : b0;  H.u[1] = loQuad ? a1 : b1;
            H.u[2] = loQuad ? a2 : b2;  H.u[3] = loQuad ? a3 : b3;
            unsigned c0 = __shfl((int)pk01l[0][tj], srcA, 64);
            unsigned c1 = __shfl((int)pk23l[0][tj], srcA, 64);
            unsigned c2 = __shfl((int)pk01l[0][tj], srcB, 64);
            unsigned c3 = __shfl((int)pk23l[0][tj], srcB, 64);
            unsigned d0_ = __shfl((int)pk01l[1][tj], srcA, 64);
            unsigned d1 = __shfl((int)pk23l[1][tj], srcA, 64);
            unsigned d2 = __shfl((int)pk01l[1][tj], srcB, 64);
            unsigned d3 = __shfl((int)pk23l[1][tj], srcB, 64);
            L.u[0] = loQuad ? c0 : d0_; L.u[1] = loQuad ? c1 : d1;
            L.u[2] = loQuad ? c2 : d2;  L.u[3] = loQuad ? c3 : d3;
            pfh[tj] = H.v; pfl[tj] = L.v;
        }
        // ---- main: acc[d][t] += D x P  (D A-frags from LDS, 2 halves)
#pragma unroll
        for (int half = 0; half < 2; half++) {
            bf16x8 dfh[4], dfl[4];
#pragma unroll
            for (int i = 0; i < 4; i++) {
                const int row = ((half*4 + i)*16 + l15) * DLSTR;
                dfh[i] = ld8(&Ds[row + qd*8]);
                dfl[i] = ld8(&Ds[row + 32 + qd*8]);
            }
#pragma unroll
            for (int i = 0; i < 4; i++)
#pragma unroll
                for (int tj = 0; tj < 2; tj++) {
                    acc[half*4+i][tj] = __builtin_amdgcn_mfma_f32_16x16x32_bf16(
                        dfh[i], pfh[tj], acc[half*4+i][tj], 0, 0, 0);
                    acc[half*4+i][tj] = __builtin_amdgcn_mfma_f32_16x16x32_bf16(
                        dfh[i], pfl[tj], acc[half*4+i][tj], 0, 0, 0);
                    acc[half*4+i][tj] = __builtin_amdgcn_mfma_f32_16x16x32_bf16(
                        dfl[i], pfh[tj], acc[half*4+i][tj], 0, 0, 0);
                }
        }
    }

    // ---- finalize row sums: reduce across quads (lane bits 4,5)
#pragma unroll
    for (int tj = 0; tj < 2; tj++) {
        rs[tj] += __shfl_xor(rs[tj], 16);
        rs[tj] += __shfl_xor(rs[tj], 32);
    }

    const float lam = 1.f / (1.f + __expf(-llam[0]));
    const float oml = 1.f - lam;
    bf16_t* DToutg = (FINAL ? (bf16_t*)nullptr : DTout + (size_t)bh * TDS);

#pragma unroll
    for (int tj = 0; tj < 2; tj++) {
        const int t = Tw + tj*16 + l15;          // C col (global t)
        const float s = lam / rs[tj];
#pragma unroll
        for (int it = 0; it < 8; it++) {
            const int d0 = it*16 + qd*4;         // C rows d0..d0+3
            float v[4];
#pragma unroll
            for (int r = 0; r < 4; r++) {
                const size_t ro = (size_t)(d0 + r)*2048 + t;
                float res = (float)DTh[ro] + (float)DTh[ro + 1024];
                v[r] = oml*res + s*acc[it][tj][r];
            }
            if (FINAL) {
                *(float4*)&Dc[((size_t)bh*Tc + t)*128 + d0] =
                    make_float4(v[0], v[1], v[2], v[3]);
            } else {
#pragma unroll
                for (int r = 0; r < 4; r++) {
                    const size_t ro = (size_t)(d0 + r)*2048 + t;
                    bf16_t h = (bf16_t)v[r];
                    DToutg[ro]        = h;
                    DToutg[ro + 1024] = (bf16_t)(v[r] - (float)h);
                }
            }
        }
    }
}

// ---------------------------------------------------------------------------
// mean over T, two-stage for full-GPU occupancy
// ---------------------------------------------------------------------------
__global__ __launch_bounds__(256)
void mean1_k(const float* __restrict__ D,
             float* __restrict__ M1re, float* __restrict__ M1im)
{
    __shared__ float sre[4][64], sim[4][64];
    const int bh = blockIdx.x, y = blockIdx.y;
    const int d = threadIdx.x & 63, q = threadIdx.x >> 6;
    const float* p = D + (size_t)bh * TD2;
    float ar = 0.f, ai = 0.f;
    const int t0 = y*128 + q*32;
    for (int t = t0; t < t0 + 32; t++) {
        ar += p[t*128 + d]; ai += p[t*128 + 64 + d];
    }
    sre[q][d] = ar; sim[q][d] = ai;
    __syncthreads();
    if (threadIdx.x < 64) {
        M1re[(bh*8 + y)*64 + d] = sre[0][d]+sre[1][d]+sre[2][d]+sre[3][d];
        M1im[(bh*8 + y)*64 + d] = sim[0][d]+sim[1][d]+sim[2][d]+sim[3][d];
    }
}

__global__ __launch_bounds__(64)
void mean2_k(const float* __restrict__ M1re, const float* __restrict__ M1im,
             float* __restrict__ Mre, float* __restrict__ Mim)
{
    const int bh = blockIdx.x, d = threadIdx.x;
    float r = 0.f, im = 0.f;
    for (int y = 0; y < 8; y++) {
        r  += M1re[(bh*8 + y)*64 + d];
        im += M1im[(bh*8 + y)*64 + d];
    }
    Mre[bh*64 + d] = r  * (1.f/1024.f);
    Mim[bh*64 + d] = im * (1.f/1024.f);
}

// ---------------------------------------------------------------------------
// gate softmax over T, two-stage (partial denominators, then normalize+emit)
// ---------------------------------------------------------------------------
__global__ __launch_bounds__(256)
void gate1_k(const float* __restrict__ D,
             const float* __restrict__ Mre, const float* __restrict__ Mim,
             float* __restrict__ Gp)
{
    __shared__ float part[4][64];
    const int bh = blockIdx.x, y = blockIdx.y;
    const int d = threadIdx.x & 63, q = threadIdx.x >> 6;
    const float* p = D + (size_t)bh * TD2;
    const float mre = Mre[bh*64 + d], mim = Mim[bh*64 + d];
    const float mabs = sqrtf(mre*mre + mim*mim);

    float ps = 0.f;
    const int t0 = y*128 + q*32;
    for (int t = t0; t < t0 + 32; t++) {
        float dr = p[t*128 + d], dv = p[t*128 + 64 + d];
        float c = (dr*mre + dv*mim) / (sqrtf(dr*dr + dv*dv)*mabs + 1e-8f);
        ps += __expf(c);
    }
    part[q][d] = ps;
    __syncthreads();
    if (threadIdx.x < 64)
        Gp[(bh*8 + y)*64 + d] = part[0][d]+part[1][d]+part[2][d]+part[3][d];
}

__global__ __launch_bounds__(256)
void gate2_k(const float* __restrict__ D,
             const float* __restrict__ Mre, const float* __restrict__ Mim,
             const float* __restrict__ V, const float* __restrict__ Gp,
             float* __restrict__ gate_out,
             bf16_t* __restrict__ gVh, bf16_t* __restrict__ gVl)
{
    __shared__ float dinv[64];
    const int bh = blockIdx.x, y = blockIdx.y;
    const int d = threadIdx.x & 63, q = threadIdx.x >> 6;
    if (threadIdx.x < 64) {
        float s = 0.f;
        for (int yy = 0; yy < 8; yy++) s += Gp[(bh*8 + yy)*64 + d];
        dinv[d] = 1.f / s;
    }
    __syncthreads();

    const float* p = D + (size_t)bh * TD2;
    const float mre = Mre[bh*64 + d], mim = Mim[bh*64 + d];
    const float mabs = sqrtf(mre*mre + mim*mim);
    const float di_ = dinv[d];
    const int b = bh >> 4, hh = bh & 15;
    const float* pv = V + (size_t)bh * TD;
    const int t0 = y*128 + q*32;
    for (int t = t0; t < t0 + 32; t++) {
        float dr = p[t*128 + d], dv = p[t*128 + 64 + d];
        float c = (dr*mre + dv*mim) / (sqrtf(dr*dr + dv*dv)*mabs + 1e-8f);
        float g = __expf(c) * di_;
        gate_out[(size_t)bh*TD + t*64 + d] = g;
        float gv = g * pv[t*64 + d];
        size_t o = ((size_t)b*Tc + t)*DMc + hh*64 + d;
        bf16_t gh = (bf16_t)gv;
        gVh[o] = gh;
        gVl[o] = (bf16_t)(gv - (float)gh);
    }
}

// ---------------------------------------------------------------------------
extern "C" void kernel_launch(void* const* d_in, const int* in_sizes, int n_in,
                              void* d_out, int out_size, void* d_ws, size_t ws_size,
                              hipStream_t stream)
{
    const float* x    = (const float*)d_in[0];
    const float* W_Q  = (const float*)d_in[1];
    const float* W_K  = (const float*)d_in[2];
    const float* W_re = (const float*)d_in[3];
    const float* W_im = (const float*)d_in[4];
    const float* W_V  = (const float*)d_in[5];
    const float* W_O  = (const float*)d_in[6];
    const float* llam = (const float*)d_in[7];

    float* out      = (float*)d_out;
    float* gate_out = out + (size_t)Mc * DMc;

    float* ws = (float*)d_ws;
    const size_t M1 = 1024*1024;
    float*  Dc  = ws;                          // 32 MB — aliases DT1
    bf16_t* DT1 = (bf16_t*)ws;                 // 16M bf16
    bf16_t* DT0 = (bf16_t*)(ws + 8*M1);        // 16M bf16 (32 MB)
    float*  V   = ws + 16*M1;                  // 16 MB
    bf16_t* Qs  = (bf16_t*)(ws + 20*M1);       // 16 MB
    bf16_t* Ksb = (bf16_t*)(ws + 24*M1);       // 16 MB
    float*  Mre = ws + 28*M1;
    float*  Mim = Mre + 4096;
    bf16_t* xh  = (bf16_t*)(ws + 28*M1 + 8192);// 8 MB
    bf16_t* xl  = xh + 4*M1;                   // 8 MB
    bf16_t* WT  = xl + 4*M1;                   // 24 MB
    bf16_t* gVh = xh;                          // alias: x dead after mgemm<0>
    bf16_t* gVl = xl;
    // scratch for mean/gate two-stage: Ksb region (dead after prop_k)
    float* Gp   = ws + 24*M1;                  // 64*8*64 f32
    float* M1re = Gp + 32768;
    float* M1im = M1re + 32768;
    // K-slice partials for mgemm<1> (K-split x2): DT0 region, dead after prop.
    float* P0 = ws + 8*M1;
    float* P1 = ws + 12*M1;

    convx_k<<<4096, 256, 0, stream>>>(x, xh, xl);
    convw_k<<<dim3(32, 32, 6), 256, 0, stream>>>(
        W_Q, W_K, W_re, W_im, W_V, W_O, WT);

    // projections (sel-paired): by>>3 = {Q,K}, {Dre,Dim}, {V}
    mgemm_k<0><<<dim3(32, 24), 256, 0, stream>>>(
        xh, xl, WT, Qs, Ksb, DT0, V, nullptr);

    prop_k<0><<<dim3(64, 8), 256, 0, stream>>>(Qs, Ksb, DT0, DT1, nullptr, llam);
    prop_k<0><<<dim3(64, 8), 256, 0, stream>>>(Qs, Ksb, DT1, DT0, nullptr, llam);
    prop_k<1><<<dim3(64, 8), 256, 0, stream>>>(Qs, Ksb, DT0, nullptr, Dc, llam);

    mean1_k<<<dim3(64, 8), 256, 0, stream>>>(Dc, M1re, M1im);
    mean2_k<<<64, 64, 0, stream>>>(M1re, M1im, Mre, Mim);
    gate1_k<<<dim3(64, 8), 256, 0, stream>>>(Dc, Mre, Mim, Gp);
    gate2_k<<<dim3(64, 8), 256, 0, stream>>>(Dc, Mre, Mim, V, Gp,
                                             gate_out, gVh, gVl);

    // out = gateV @ W_O, K-split x2 into partials, then reduce
    mgemm_k<1><<<dim3(32, 8, 2), 256, 0, stream>>>(
        gVh, gVl, WT, nullptr, nullptr, nullptr, nullptr, P0);
    reduce2_k<<<4096, 256, 0, stream>>>(P0, P1, out);
}